// Round 10
// baseline (7469.096 us; speedup 1.0000x reference)
//
#include <hip/hip_runtime.h>
#include <hip/hip_bf16.h>

#define NPTS 8192
#define DIM 32
#define KKDE 32
#define KRIPS 16
#define DESTNUM 10

__device__ __forceinline__ unsigned long long shfl_xor_u64(unsigned long long v, int m) {
  int lo = __shfl_xor((int)(unsigned)(v & 0xFFFFFFFFull), m, 64);
  int hi = __shfl_xor((int)(unsigned)(v >> 32), m, 64);
  return (((unsigned long long)(unsigned)hi) << 32) | (unsigned)lo;
}

// ---------------- dtype detector: is x bf16-packed or f32? ----------------
__global__ __launch_bounds__(64) void detect_kernel(const unsigned short* __restrict__ x,
                                                    int* __restrict__ flag) {
  int lane = threadIdx.x;
  unsigned u = x[2 * lane];
  int e = (u >> 7) & 0xFF;
  bool pass = (e >= 110 && e <= 130);
  unsigned long long b = __ballot(pass);
  if (lane == 0) flag[0] = (__popcll(b) >= 32) ? 1 : 0;
}

// ---------------- squared norms (chain bitwise-identical to knn's old inline sqj) ----------------
__global__ __launch_bounds__(256) void sq_kernel(const unsigned short* __restrict__ xh,
                                                 const int* __restrict__ flag,
                                                 float* __restrict__ sqv) {
  int p = blockIdx.x * 256 + threadIdx.x;
  if (p >= NPTS) return;
  const bool isbf16 = (flag[0] != 0);
  const float* xf = (const float*)xh;
  float e[DIM];
  if (isbf16) {
    const uint4* xj = (const uint4*)(xh + p * DIM);
#pragma unroll
    for (int q = 0; q < DIM / 8; ++q) {
      uint4 w = xj[q];
      e[q * 8 + 0] = __uint_as_float(w.x << 16);
      e[q * 8 + 1] = __uint_as_float(w.x & 0xFFFF0000u);
      e[q * 8 + 2] = __uint_as_float(w.y << 16);
      e[q * 8 + 3] = __uint_as_float(w.y & 0xFFFF0000u);
      e[q * 8 + 4] = __uint_as_float(w.z << 16);
      e[q * 8 + 5] = __uint_as_float(w.z & 0xFFFF0000u);
      e[q * 8 + 6] = __uint_as_float(w.w << 16);
      e[q * 8 + 7] = __uint_as_float(w.w & 0xFFFF0000u);
    }
  } else {
    const float4* xj = (const float4*)(xf + p * DIM);
#pragma unroll
    for (int q = 0; q < DIM / 4; ++q) {
      float4 w = xj[q];
      e[q * 4 + 0] = w.x; e[q * 4 + 1] = w.y;
      e[q * 4 + 2] = w.z; e[q * 4 + 3] = w.w;
    }
  }
  float s = 0.f;
#pragma unroll
  for (int q = 0; q < DIM; ++q) s = fmaf(e[q], e[q], s);
  sqv[p] = s;
}

// ---------------- kNN v2: register d2 + per-wave radix bracket + bitonic ----------------
// One block per row i. d2 values bitwise-identical to R9 (same fma chains; diag
// cancels exactly since dot_ii chain == sq_kernel chain). Selection: per-wave
// binary search on value bits (no LDS/syncs) -> <=64 candidates -> in-wave
// bitonic sort of (valbits<<32|j) keys (ties -> lower j, == jax top_k) -> 2
// merge rounds -> ascending top-32.
__global__ __launch_bounds__(256, 4) void knn_kernel(const unsigned short* __restrict__ xh,
                                                     const int* __restrict__ flag,
                                                     const float* __restrict__ sqv,
                                                     float* __restrict__ kde,
                                                     int* __restrict__ rips) {
  __shared__ float xis[DIM];
  __shared__ int flagS;
  __shared__ int cnt[4];
  __shared__ unsigned long long cand[4 * 64];  // 2 KB
  __shared__ unsigned long long srt[4 * 32];   // 1 KB
  __shared__ unsigned long long fin[64];       // 512 B
  __shared__ float knnv[KKDE];
  __shared__ int knni[KKDE];
  const int i = blockIdx.x;
  const int t = threadIdx.x;
  const int w = t >> 6, lane = t & 63;
  if (t == 0) flagS = flag[0];
  __syncthreads();
  const bool isbf16 = (flagS != 0);
  const float* xf = (const float*)xh;
  if (t < DIM)
    xis[t] = isbf16 ? __uint_as_float(((unsigned)xh[i * DIM + t]) << 16)
                    : xf[i * DIM + t];
  __syncthreads();
  float xi[DIM];
#pragma unroll
  for (int q = 0; q < DIM; ++q) xi[q] = xis[q];
  const float sqi = sqv[i];
  // ---- compute phase: d2 for this thread's 32 strided j into registers ----
  float r[32];
#pragma unroll
  for (int s = 0; s < 32; ++s) {
    const int j = t + (s << 8);
    float xr[DIM];
    if (isbf16) {
      const uint4* xj = (const uint4*)(xh + j * DIM);
#pragma unroll
      for (int q = 0; q < DIM / 8; ++q) {
        uint4 wv = xj[q];
        xr[q * 8 + 0] = __uint_as_float(wv.x << 16);
        xr[q * 8 + 1] = __uint_as_float(wv.x & 0xFFFF0000u);
        xr[q * 8 + 2] = __uint_as_float(wv.y << 16);
        xr[q * 8 + 3] = __uint_as_float(wv.y & 0xFFFF0000u);
        xr[q * 8 + 4] = __uint_as_float(wv.z << 16);
        xr[q * 8 + 5] = __uint_as_float(wv.z & 0xFFFF0000u);
        xr[q * 8 + 6] = __uint_as_float(wv.w << 16);
        xr[q * 8 + 7] = __uint_as_float(wv.w & 0xFFFF0000u);
      }
    } else {
      const float4* xj = (const float4*)(xf + j * DIM);
#pragma unroll
      for (int q = 0; q < DIM / 4; ++q) {
        float4 wv = xj[q];
        xr[q * 4 + 0] = wv.x; xr[q * 4 + 1] = wv.y;
        xr[q * 4 + 2] = wv.z; xr[q * 4 + 3] = wv.w;
      }
    }
    float dot = 0.f;
#pragma unroll
    for (int q = 0; q < DIM; ++q) dot = fmaf(xi[q], xr[q], dot);
    // j==i: dot == sqi == sqv[j] bitwise -> fmaf(-2,s,2s) == 0 exactly
    r[s] = fmaxf(fmaf(-2.f, dot, sqi + sqv[j]), 0.f);
  }
  // ---- per-wave binary search: smallest T with count(<=T) >= 32, count <= 64 ----
  unsigned lo = 0u, hi = 0x7F800000u;
  int chi = 2048;
  while (chi > 64 && (hi - lo) > 1u) {
    const unsigned mid = lo + ((hi - lo) >> 1);
    int c = 0;
#pragma unroll
    for (int s = 0; s < 32; ++s) c += (__float_as_uint(r[s]) <= mid) ? 1 : 0;
#pragma unroll
    for (int m = 1; m <= 32; m <<= 1) c += __shfl_xor(c, m, 64);
    if (c >= 32) { hi = mid; chi = c; } else { lo = mid; }
  }
  // ---- compact candidates (per-wave LDS region; same-wave ops are ordered) ----
  if (lane == 0) cnt[w] = 0;
  cand[(w << 6) | lane] = ~0ull;
#pragma unroll
  for (int s = 0; s < 32; ++s) {
    if (__float_as_uint(r[s]) <= hi) {
      int pos = atomicAdd(&cnt[w], 1);
      if (pos < 64)
        cand[(w << 6) + pos] =
            (((unsigned long long)__float_as_uint(r[s])) << 32) | (unsigned)(t + (s << 8));
    }
  }
  // ---- in-wave bitonic sort of 64 keys ----
  unsigned long long v = cand[(w << 6) | lane];
#pragma unroll
  for (int k = 2; k <= 64; k <<= 1) {
#pragma unroll
    for (int j = 32; j > 0; j >>= 1) {
      if (j >= k) continue;
      unsigned long long o = shfl_xor_u64(v, j);
      bool keepMin = (((lane & k) == 0) == ((lane & j) == 0));
      v = keepMin ? (v < o ? v : o) : (v > o ? v : o);
    }
  }
  if (lane < 32) srt[(w << 5) | lane] = v;
  __syncthreads();
  // ---- merge round 1: (w0: lists 0,1) (w1: lists 2,3) ----
  if (w < 2) {
    const unsigned long long* A = &srt[(w * 2) << 5];
    const unsigned long long* B = &srt[(w * 2 + 1) << 5];
    unsigned long long m = (lane < 32) ? A[lane] : B[63 - lane];
#pragma unroll
    for (int j = 32; j > 0; j >>= 1) {
      unsigned long long o = shfl_xor_u64(m, j);
      bool keepMin = ((lane & j) == 0);
      m = keepMin ? (m < o ? m : o) : (m > o ? m : o);
    }
    if (lane < 32) fin[(w << 5) | lane] = m;
  }
  __syncthreads();
  // ---- merge round 2: wave0 merges the two 32-lists -> final ascending 32 ----
  if (w == 0) {
    unsigned long long m = (lane < 32) ? fin[lane] : fin[32 + (63 - lane)];
#pragma unroll
    for (int j = 32; j > 0; j >>= 1) {
      unsigned long long o = shfl_xor_u64(m, j);
      bool keepMin = ((lane & j) == 0);
      m = keepMin ? (m < o ? m : o) : (m > o ? m : o);
    }
    if (lane < 32) {
      knnv[lane] = __uint_as_float((unsigned)(m >> 32));
      knni[lane] = (int)(m & 0x1FFFull);
    }
  }
  __syncthreads();
  if (t == 0) {
    float s = 0.f;
    for (int k = 0; k < KKDE; ++k) s += expf(knnv[k] * -0.015625f);  // exp(-d2/64), ascending
    kde[i] = s;
  }
  if (t < KRIPS) rips[i * KRIPS + t] = knni[t];
}

// ---------------- max(kde) ----------------
__global__ __launch_bounds__(256) void max_kernel(const float* __restrict__ kde,
                                                  float* __restrict__ scalf) {
  __shared__ float red[256];
  int t = threadIdx.x;
  float m = 0.f;
  for (int p = t; p < NPTS; p += 256) m = fmaxf(m, kde[p]);
  red[t] = m;
  __syncthreads();
  for (int s = 128; s; s >>= 1) {
    if (t < s) red[t] = fmaxf(red[t], red[t + s]);
    __syncthreads();
  }
  if (t == 0) scalf[0] = red[0];
}

// ---------------- normalize + init death ----------------
__global__ __launch_bounds__(256) void norm_kernel(float* __restrict__ kde,
                                                   const float* __restrict__ scalf,
                                                   int* __restrict__ death) {
  int p = blockIdx.x * 256 + threadIdx.x;
  if (p < NPTS) {
    kde[p] = kde[p] / scalf[0];
    death[p] = -1;
  }
}

// ---------------- argmin(kde) ----------------
__global__ __launch_bounds__(256) void argmin_kernel(const float* __restrict__ kde,
                                                     int* __restrict__ scali) {
  __shared__ unsigned long long red[256];
  int t = threadIdx.x;
  unsigned long long best = ~0ull;
  for (int p = t; p < NPTS; p += 256) {
    unsigned long long kk = (((unsigned long long)__float_as_uint(kde[p])) << 32) | (unsigned)p;
    if (kk < best) best = kk;
  }
  red[t] = best;
  __syncthreads();
  for (int s = 128; s; s >>= 1) {
    if (t < s && red[t + s] < red[t]) red[t] = red[t + s];
    __syncthreads();
  }
  if (t == 0) scali[0] = (int)(red[0] & 0xFFFFFFFFull);
}

// ---------------- bitonic sort: order = argsort(-kde) (stable), rank = inverse ----------------
__global__ __launch_bounds__(256) void sort_kernel(const float* __restrict__ kde,
                                                   int* __restrict__ order,
                                                   int* __restrict__ rankp) {
  __shared__ float kv[NPTS];            // 32 KB
  __shared__ unsigned short ki[NPTS];   // 16 KB
  int t = threadIdx.x;
  for (int p = t; p < NPTS; p += 256) { kv[p] = kde[p]; ki[p] = (unsigned short)p; }
  __syncthreads();
  for (int size = 2; size <= NPTS; size <<= 1) {
    for (int stride = size >> 1; stride > 0; stride >>= 1) {
      for (int q = t; q < NPTS / 2; q += 256) {
        int lo = ((q & ~(stride - 1)) << 1) | (q & (stride - 1));
        int hi = lo + stride;
        float va = kv[lo], vb = kv[hi];
        int ia = ki[lo], ib = ki[hi];
        bool aFirst = (va > vb) || (va == vb && ia < ib);
        bool up = ((lo & size) == 0);
        if (up != aFirst) {
          kv[lo] = vb; kv[hi] = va;
          ki[lo] = (unsigned short)ib; ki[hi] = (unsigned short)ia;
        }
      }
      __syncthreads();
    }
  }
  for (int p = t; p < NPTS; p += 256) {
    int idx = ki[p];
    order[p] = idx;
    rankp[idx] = p;
  }
}

// ---------------- ordered neighbor stream (flat: [t*16 + kk]) ----------------
__global__ __launch_bounds__(256) void onbr_kernel(const int* __restrict__ order,
                                                   const int* __restrict__ rankp,
                                                   const int* __restrict__ rips,
                                                   unsigned short* __restrict__ onbr) {
  int e = blockIdx.x * 256 + threadIdx.x;  // e < NPTS*KRIPS
  if (e >= NPTS * KRIPS) return;
  int t = e >> 4, kk = e & 15;
  int i = order[t];
  int nbr = rips[i * KRIPS + kk];
  bool valid = rankp[nbr] < t;  // self has rank == t -> invalid, matching ref
  onbr[e] = (unsigned short)(nbr | (valid ? 0x8000 : 0));
}

// ---------------- persistence scan: eagerly-compressed union-find (R9, proven) ----------------
__global__ __launch_bounds__(64) void scan_kernel(const float* __restrict__ kde,
                                                  const int* __restrict__ order,
                                                  const unsigned short* __restrict__ onbr,
                                                  int* __restrict__ death,
                                                  const int* __restrict__ scali) {
  __shared__ float kdeS[NPTS];          // 32 KB
  __shared__ unsigned short root[NPTS]; // 16 KB
  const int lane = threadIdx.x;
  for (int p = lane; p < NPTS; p += 64) { kdeS[p] = kde[p]; root[p] = (unsigned short)p; }
  __syncthreads();
  const int sg = lane >> 4;
  const int4* ord4 = (const int4*)order;
  unsigned long long* root64 = (unsigned long long*)root;
  unsigned short curD = onbr[lane];
  int4 curI = ord4[0];
  const int NG = NPTS / 4;
  for (int grp = 0; grp < NG; ++grp) {
    unsigned short nxtD = 0;
    int4 nxtI = make_int4(0, 0, 0, 0);
    if (grp + 1 < NG) {
      nxtD = onbr[(grp + 1) * 64 + lane];
      nxtI = ord4[grp + 1];
    }
    const int di = curD;
    const int nbr = di & 0x1FFF;
    const bool valid = (di & 0x8000) != 0;
    const int iMine = (sg == 0) ? curI.x : (sg == 1) ? curI.y : (sg == 2) ? curI.z : curI.w;
    const int rd = root[nbr];           // single-hop find (invariant)
    const unsigned long long vbAll = __ballot(valid);
    const unsigned long long vb0 = vbAll & 0xFFFFull;
    const unsigned long long vb1 = (vbAll >> 16) & 0xFFFFull;
    const unsigned long long vb2 = (vbAll >> 32) & 0xFFFFull;
    const unsigned long long vb3 = (vbAll >> 48) & 0xFFFFull;
    const int gc0 = vb0 ? __builtin_amdgcn_readlane(rd, __ffsll(vb0) - 1) : curI.x;
    const int gc1 = vb1 ? __builtin_amdgcn_readlane(rd, 16 + __ffsll(vb1) - 1) : curI.y;
    const int gc2 = vb2 ? __builtin_amdgcn_readlane(rd, 32 + __ffsll(vb2) - 1) : curI.z;
    const int gc3 = vb3 ? __builtin_amdgcn_readlane(rd, 48 + __ffsll(vb3) - 1) : curI.w;
    const int gcMine = (sg == 0) ? gc0 : (sg == 1) ? gc1 : (sg == 2) ? gc2 : gc3;
    const bool uniOk = !valid || (rd == gcMine);
    const bool collide =
        valid && (rd == curI.x || rd == curI.y || rd == curI.z || rd == curI.w);
    if (__all(uniOk && !collide)) {
      if ((lane & 15) == 0) root[iMine] = (unsigned short)gcMine;
    } else {
#pragma unroll
      for (int s = 0; s < 4; ++s) {
        const unsigned long long smask = 0xFFFFull << (16 * s);
        const int rc = (s == 0) ? rd : (int)root[nbr];
        unsigned long long vb = vbAll & smask;
        if (vb != 0) {
          int cl = __ffsll(vb) - 1;
          int gc = __builtin_amdgcn_readlane(rc, cl);
          unsigned long long uni = __ballot(!valid || rc == gc) & smask;
          if (uni == smask) {
            if (lane == 16 * s) root[iMine] = (unsigned short)gc;
          } else {
            float kr = valid ? kdeS[rc] : -1.0f;
            float mx = kr;
#pragma unroll
            for (int mk = 1; mk <= 8; mk <<= 1) mx = fmaxf(mx, __shfl_xor(mx, mk, 64));
            unsigned long long b = __ballot(valid && kr == mx) & smask;
            int kwin = __ffsll(b) - 1;
            int g = __builtin_amdgcn_readlane(rc, kwin);
            bool dying = (sg == s) && valid && (rc != g);
            if (dying) {
              root[rc] = (unsigned short)g;
              death[rc] = iMine;
            }
            if (lane == 16 * s) root[iMine] = (unsigned short)g;
#pragma unroll 1
            for (int it = 0; it < NPTS / 256; ++it) {
              int idx = it * 64 + lane;
              unsigned long long wv = root64[idx];
              unsigned e0 = (unsigned)(wv & 0xFFFFull);
              unsigned e1 = (unsigned)((wv >> 16) & 0xFFFFull);
              unsigned e2 = (unsigned)((wv >> 32) & 0xFFFFull);
              unsigned e3 = (unsigned)((wv >> 48) & 0xFFFFull);
              e0 = root[e0]; e1 = root[e1]; e2 = root[e2]; e3 = root[e3];
              root64[idx] = (unsigned long long)e0 | ((unsigned long long)e1 << 16) |
                            ((unsigned long long)e2 << 32) | ((unsigned long long)e3 << 48);
            }
          }
        }
      }
    }
    curD = nxtD;
    curI = nxtI;
  }
  if (lane == 0) death[order[0]] = scali[0];  // essential pair
}

// ---------------- loss: top-10 persistence, l_change + l_salient (f32 out) ----------------
__global__ __launch_bounds__(256) void loss_kernel(const float* __restrict__ kde,
                                                   const int* __restrict__ death,
                                                   float* __restrict__ out) {
  __shared__ float redv[256];
  __shared__ int redi[256];
  const int t = threadIdx.x;
  int chosen[DESTNUM];
  for (int k = 0; k < DESTNUM; ++k) {
    float bv = -__builtin_inff();
    int bi = 1 << 30;
    for (int p = t; p < NPTS; p += 256) {
      int d = death[p];
      if (d < 0) continue;
      bool used = false;
      for (int c = 0; c < k; ++c) used |= (chosen[c] == p);
      if (used) continue;
      float pers = kde[p] - kde[d];
      if (pers > bv || (pers == bv && p < bi)) { bv = pers; bi = p; }
    }
    redv[t] = bv; redi[t] = bi;
    __syncthreads();
    for (int s = 128; s; s >>= 1) {
      if (t < s) {
        if (redv[t + s] > redv[t] || (redv[t + s] == redv[t] && redi[t + s] < redi[t])) {
          redv[t] = redv[t + s];
          redi[t] = redi[t + s];
        }
      }
      __syncthreads();
    }
    chosen[k] = redi[0];
    __syncthreads();
  }
  float acc = 0.f;
  for (int p = t; p < NPTS; p += 256) {
    int d = death[p];
    if (d < 0) continue;
    bool sal = false;
    for (int c = 0; c < DESTNUM; ++c) sal |= (chosen[c] == p);
    float dv = kde[d];
    float kp = kde[p];
    acc += sal ? ((kp - 1.f) * (kp - 1.f) + dv * dv) : (kp - dv) * (kp - dv);
  }
  redv[t] = acc;
  __syncthreads();
  for (int s = 128; s; s >>= 1) {
    if (t < s) redv[t] += redv[t + s];
    __syncthreads();
  }
  if (t == 0) out[0] = redv[0];
}

extern "C" void kernel_launch(void* const* d_in, const int* in_sizes, int n_in,
                              void* d_out, int out_size, void* d_ws, size_t ws_size,
                              hipStream_t stream) {
  const unsigned short* x = (const unsigned short*)d_in[0];

  float* kde = (float*)d_ws;                      // NPTS f32
  float* scalf = kde + NPTS;                      // [0] = kdemax
  int* scali = (int*)(scalf + 64);                // [0] = argmin idx
  int* flag = scali + 64;                         // [0] = dtype flag (1=bf16, 0=f32)
  float* sqv = (float*)(flag + 64);               // NPTS squared norms
  int* order = (int*)(sqv + NPTS);                // NPTS (16B-aligned for int4 loads)
  int* rankp = order + NPTS;                      // NPTS
  int* rips = rankp + NPTS;                       // NPTS*KRIPS
  unsigned short* onbr = (unsigned short*)(rips + NPTS * KRIPS);  // NPTS*KRIPS u16
  int* death = (int*)(onbr + NPTS * KRIPS);       // NPTS

  hipLaunchKernelGGL(detect_kernel, dim3(1), dim3(64), 0, stream, x, flag);
  hipLaunchKernelGGL(sq_kernel, dim3(NPTS / 256), dim3(256), 0, stream, x, flag, sqv);
  hipLaunchKernelGGL(knn_kernel, dim3(NPTS), dim3(256), 0, stream, x, flag, sqv, kde, rips);
  hipLaunchKernelGGL(max_kernel, dim3(1), dim3(256), 0, stream, kde, scalf);
  hipLaunchKernelGGL(norm_kernel, dim3(NPTS / 256), dim3(256), 0, stream, kde, scalf, death);
  hipLaunchKernelGGL(argmin_kernel, dim3(1), dim3(256), 0, stream, kde, scali);
  hipLaunchKernelGGL(sort_kernel, dim3(1), dim3(256), 0, stream, kde, order, rankp);
  hipLaunchKernelGGL(onbr_kernel, dim3(NPTS * KRIPS / 256), dim3(256), 0, stream,
                     order, rankp, rips, onbr);
  hipLaunchKernelGGL(scan_kernel, dim3(1), dim3(64), 0, stream, kde, order, onbr, death, scali);
  hipLaunchKernelGGL(loss_kernel, dim3(1), dim3(256), 0, stream, kde, death, (float*)d_out);
}

// Round 11
// 4888.939 us; speedup vs baseline: 1.5278x; 1.5278x over previous
//
#include <hip/hip_runtime.h>
#include <hip/hip_bf16.h>

#define NPTS 8192
#define DIM 32
#define KKDE 32
#define KRIPS 16
#define DESTNUM 10

__device__ __forceinline__ unsigned long long shfl_xor_u64(unsigned long long v, int m) {
  int lo = __shfl_xor((int)(unsigned)(v & 0xFFFFFFFFull), m, 64);
  int hi = __shfl_xor((int)(unsigned)(v >> 32), m, 64);
  return (((unsigned long long)(unsigned)hi) << 32) | (unsigned)lo;
}

// ---------------- dtype detector: is x bf16-packed or f32? ----------------
__global__ __launch_bounds__(64) void detect_kernel(const unsigned short* __restrict__ x,
                                                    int* __restrict__ flag) {
  int lane = threadIdx.x;
  unsigned u = x[2 * lane];
  int e = (u >> 7) & 0xFF;
  bool pass = (e >= 110 && e <= 130);
  unsigned long long b = __ballot(pass);
  if (lane == 0) flag[0] = (__popcll(b) >= 32) ? 1 : 0;
}

// ---------------- squared norms (chain bitwise-identical to knn's dot chain) ----------------
__global__ __launch_bounds__(256) void sq_kernel(const unsigned short* __restrict__ xh,
                                                 const int* __restrict__ flag,
                                                 float* __restrict__ sqv) {
  int p = blockIdx.x * 256 + threadIdx.x;
  if (p >= NPTS) return;
  const bool isbf16 = (flag[0] != 0);
  const float* xf = (const float*)xh;
  float e[DIM];
  if (isbf16) {
    const uint4* xj = (const uint4*)(xh + p * DIM);
#pragma unroll
    for (int q = 0; q < DIM / 8; ++q) {
      uint4 w = xj[q];
      e[q * 8 + 0] = __uint_as_float(w.x << 16);
      e[q * 8 + 1] = __uint_as_float(w.x & 0xFFFF0000u);
      e[q * 8 + 2] = __uint_as_float(w.y << 16);
      e[q * 8 + 3] = __uint_as_float(w.y & 0xFFFF0000u);
      e[q * 8 + 4] = __uint_as_float(w.z << 16);
      e[q * 8 + 5] = __uint_as_float(w.z & 0xFFFF0000u);
      e[q * 8 + 6] = __uint_as_float(w.w << 16);
      e[q * 8 + 7] = __uint_as_float(w.w & 0xFFFF0000u);
    }
  } else {
    const float4* xj = (const float4*)(xf + p * DIM);
#pragma unroll
    for (int q = 0; q < DIM / 4; ++q) {
      float4 w = xj[q];
      e[q * 4 + 0] = w.x; e[q * 4 + 1] = w.y;
      e[q * 4 + 2] = w.z; e[q * 4 + 3] = w.w;
    }
  }
  float s = 0.f;
#pragma unroll
  for (int q = 0; q < DIM; ++q) s = fmaf(e[q], e[q], s);
  sqv[p] = s;
}

// ---------------- kNN v2: register d2 + per-wave radix bracket + bitonic ----------------
// One block per row i. d2 bitwise-identical to R9. min-waves=1: VGPR cap 512 so
// xi[32]+r[32] stay in registers — R10's (256,4) cap of 128 forced a 15.7 GB
// scratch spill (WRITE_SIZE 10.9 GB) and a 5x regression.
__global__ __launch_bounds__(256, 1) void knn_kernel(const unsigned short* __restrict__ xh,
                                                     const int* __restrict__ flag,
                                                     const float* __restrict__ sqv,
                                                     float* __restrict__ kde,
                                                     int* __restrict__ rips) {
  __shared__ float xis[DIM];
  __shared__ int flagS;
  __shared__ int cnt[4];
  __shared__ unsigned long long cand[4 * 64];  // 2 KB
  __shared__ unsigned long long srt[4 * 32];   // 1 KB
  __shared__ unsigned long long fin[64];       // 512 B
  __shared__ float knnv[KKDE];
  __shared__ int knni[KKDE];
  const int i = blockIdx.x;
  const int t = threadIdx.x;
  const int w = t >> 6, lane = t & 63;
  if (t == 0) flagS = flag[0];
  __syncthreads();
  const bool isbf16 = (flagS != 0);
  const float* xf = (const float*)xh;
  if (t < DIM)
    xis[t] = isbf16 ? __uint_as_float(((unsigned)xh[i * DIM + t]) << 16)
                    : xf[i * DIM + t];
  __syncthreads();
  float xi[DIM];
#pragma unroll
  for (int q = 0; q < DIM; ++q) xi[q] = xis[q];
  const float sqi = sqv[i];
  // ---- compute phase: d2 for this thread's 32 strided j into registers ----
  float r[32];
#pragma unroll
  for (int s = 0; s < 32; ++s) {
    const int j = t + (s << 8);
    float xr[DIM];
    if (isbf16) {
      const uint4* xj = (const uint4*)(xh + j * DIM);
#pragma unroll
      for (int q = 0; q < DIM / 8; ++q) {
        uint4 wv = xj[q];
        xr[q * 8 + 0] = __uint_as_float(wv.x << 16);
        xr[q * 8 + 1] = __uint_as_float(wv.x & 0xFFFF0000u);
        xr[q * 8 + 2] = __uint_as_float(wv.y << 16);
        xr[q * 8 + 3] = __uint_as_float(wv.y & 0xFFFF0000u);
        xr[q * 8 + 4] = __uint_as_float(wv.z << 16);
        xr[q * 8 + 5] = __uint_as_float(wv.z & 0xFFFF0000u);
        xr[q * 8 + 6] = __uint_as_float(wv.w << 16);
        xr[q * 8 + 7] = __uint_as_float(wv.w & 0xFFFF0000u);
      }
    } else {
      const float4* xj = (const float4*)(xf + j * DIM);
#pragma unroll
      for (int q = 0; q < DIM / 4; ++q) {
        float4 wv = xj[q];
        xr[q * 4 + 0] = wv.x; xr[q * 4 + 1] = wv.y;
        xr[q * 4 + 2] = wv.z; xr[q * 4 + 3] = wv.w;
      }
    }
    float dot = 0.f;
#pragma unroll
    for (int q = 0; q < DIM; ++q) dot = fmaf(xi[q], xr[q], dot);
    // j==i: dot == sqi == sqv[j] bitwise -> fmaf(-2,s,2s) == 0 exactly
    r[s] = fmaxf(fmaf(-2.f, dot, sqi + sqv[j]), 0.f);
  }
  // ---- per-wave binary search: smallest T with count(<=T) >= 32, count <= 64 ----
  unsigned lo = 0u, hi = 0x7F800000u;
  int chi = 2048;
  while (chi > 64 && (hi - lo) > 1u) {
    const unsigned mid = lo + ((hi - lo) >> 1);
    int c = 0;
#pragma unroll
    for (int s = 0; s < 32; ++s) c += (__float_as_uint(r[s]) <= mid) ? 1 : 0;
#pragma unroll
    for (int m = 1; m <= 32; m <<= 1) c += __shfl_xor(c, m, 64);
    if (c >= 32) { hi = mid; chi = c; } else { lo = mid; }
  }
  // ---- compact candidates (per-wave LDS region; same-wave ops are ordered) ----
  if (lane == 0) cnt[w] = 0;
  cand[(w << 6) | lane] = ~0ull;
#pragma unroll
  for (int s = 0; s < 32; ++s) {
    if (__float_as_uint(r[s]) <= hi) {
      int pos = atomicAdd(&cnt[w], 1);
      if (pos < 64)
        cand[(w << 6) + pos] =
            (((unsigned long long)__float_as_uint(r[s])) << 32) | (unsigned)(t + (s << 8));
    }
  }
  // ---- in-wave bitonic sort of 64 keys ----
  unsigned long long v = cand[(w << 6) | lane];
#pragma unroll
  for (int k = 2; k <= 64; k <<= 1) {
#pragma unroll
    for (int j = 32; j > 0; j >>= 1) {
      if (j >= k) continue;
      unsigned long long o = shfl_xor_u64(v, j);
      bool keepMin = (((lane & k) == 0) == ((lane & j) == 0));
      v = keepMin ? (v < o ? v : o) : (v > o ? v : o);
    }
  }
  if (lane < 32) srt[(w << 5) | lane] = v;
  __syncthreads();
  // ---- merge round 1: (w0: lists 0,1) (w1: lists 2,3) ----
  if (w < 2) {
    const unsigned long long* A = &srt[(w * 2) << 5];
    const unsigned long long* B = &srt[(w * 2 + 1) << 5];
    unsigned long long m = (lane < 32) ? A[lane] : B[63 - lane];
#pragma unroll
    for (int j = 32; j > 0; j >>= 1) {
      unsigned long long o = shfl_xor_u64(m, j);
      bool keepMin = ((lane & j) == 0);
      m = keepMin ? (m < o ? m : o) : (m > o ? m : o);
    }
    if (lane < 32) fin[(w << 5) | lane] = m;
  }
  __syncthreads();
  // ---- merge round 2: wave0 merges the two 32-lists -> final ascending 32 ----
  if (w == 0) {
    unsigned long long m = (lane < 32) ? fin[lane] : fin[32 + (63 - lane)];
#pragma unroll
    for (int j = 32; j > 0; j >>= 1) {
      unsigned long long o = shfl_xor_u64(m, j);
      bool keepMin = ((lane & j) == 0);
      m = keepMin ? (m < o ? m : o) : (m > o ? m : o);
    }
    if (lane < 32) {
      knnv[lane] = __uint_as_float((unsigned)(m >> 32));
      knni[lane] = (int)(m & 0x1FFFull);
    }
  }
  __syncthreads();
  if (t == 0) {
    float s = 0.f;
    for (int k = 0; k < KKDE; ++k) s += expf(knnv[k] * -0.015625f);  // exp(-d2/64), ascending
    kde[i] = s;
  }
  if (t < KRIPS) rips[i * KRIPS + t] = knni[t];
}

// ---------------- max(kde) ----------------
__global__ __launch_bounds__(256) void max_kernel(const float* __restrict__ kde,
                                                  float* __restrict__ scalf) {
  __shared__ float red[256];
  int t = threadIdx.x;
  float m = 0.f;
  for (int p = t; p < NPTS; p += 256) m = fmaxf(m, kde[p]);
  red[t] = m;
  __syncthreads();
  for (int s = 128; s; s >>= 1) {
    if (t < s) red[t] = fmaxf(red[t], red[t + s]);
    __syncthreads();
  }
  if (t == 0) scalf[0] = red[0];
}

// ---------------- normalize + init death ----------------
__global__ __launch_bounds__(256) void norm_kernel(float* __restrict__ kde,
                                                   const float* __restrict__ scalf,
                                                   int* __restrict__ death) {
  int p = blockIdx.x * 256 + threadIdx.x;
  if (p < NPTS) {
    kde[p] = kde[p] / scalf[0];
    death[p] = -1;
  }
}

// ---------------- argmin(kde) ----------------
__global__ __launch_bounds__(256) void argmin_kernel(const float* __restrict__ kde,
                                                     int* __restrict__ scali) {
  __shared__ unsigned long long red[256];
  int t = threadIdx.x;
  unsigned long long best = ~0ull;
  for (int p = t; p < NPTS; p += 256) {
    unsigned long long kk = (((unsigned long long)__float_as_uint(kde[p])) << 32) | (unsigned)p;
    if (kk < best) best = kk;
  }
  red[t] = best;
  __syncthreads();
  for (int s = 128; s; s >>= 1) {
    if (t < s && red[t + s] < red[t]) red[t] = red[t + s];
    __syncthreads();
  }
  if (t == 0) scali[0] = (int)(red[0] & 0xFFFFFFFFull);
}

// ---------------- bitonic sort: order = argsort(-kde) (stable), rank = inverse ----------------
__global__ __launch_bounds__(256) void sort_kernel(const float* __restrict__ kde,
                                                   int* __restrict__ order,
                                                   int* __restrict__ rankp) {
  __shared__ float kv[NPTS];            // 32 KB
  __shared__ unsigned short ki[NPTS];   // 16 KB
  int t = threadIdx.x;
  for (int p = t; p < NPTS; p += 256) { kv[p] = kde[p]; ki[p] = (unsigned short)p; }
  __syncthreads();
  for (int size = 2; size <= NPTS; size <<= 1) {
    for (int stride = size >> 1; stride > 0; stride >>= 1) {
      for (int q = t; q < NPTS / 2; q += 256) {
        int lo = ((q & ~(stride - 1)) << 1) | (q & (stride - 1));
        int hi = lo + stride;
        float va = kv[lo], vb = kv[hi];
        int ia = ki[lo], ib = ki[hi];
        bool aFirst = (va > vb) || (va == vb && ia < ib);
        bool up = ((lo & size) == 0);
        if (up != aFirst) {
          kv[lo] = vb; kv[hi] = va;
          ki[lo] = (unsigned short)ib; ki[hi] = (unsigned short)ia;
        }
      }
      __syncthreads();
    }
  }
  for (int p = t; p < NPTS; p += 256) {
    int idx = ki[p];
    order[p] = idx;
    rankp[idx] = p;
  }
}

// ---------------- ordered neighbor stream (flat: [t*16 + kk]) ----------------
__global__ __launch_bounds__(256) void onbr_kernel(const int* __restrict__ order,
                                                   const int* __restrict__ rankp,
                                                   const int* __restrict__ rips,
                                                   unsigned short* __restrict__ onbr) {
  int e = blockIdx.x * 256 + threadIdx.x;  // e < NPTS*KRIPS
  if (e >= NPTS * KRIPS) return;
  int t = e >> 4, kk = e & 15;
  int i = order[t];
  int nbr = rips[i * KRIPS + kk];
  bool valid = rankp[nbr] < t;  // self has rank == t -> invalid, matching ref
  onbr[e] = (unsigned short)(nbr | (valid ? 0x8000 : 0));
}

// ---------------- persistence scan: eagerly-compressed union-find (R9, proven) ----------------
__global__ __launch_bounds__(64) void scan_kernel(const float* __restrict__ kde,
                                                  const int* __restrict__ order,
                                                  const unsigned short* __restrict__ onbr,
                                                  int* __restrict__ death,
                                                  const int* __restrict__ scali) {
  __shared__ float kdeS[NPTS];          // 32 KB
  __shared__ unsigned short root[NPTS]; // 16 KB
  const int lane = threadIdx.x;
  for (int p = lane; p < NPTS; p += 64) { kdeS[p] = kde[p]; root[p] = (unsigned short)p; }
  __syncthreads();
  const int sg = lane >> 4;
  const int4* ord4 = (const int4*)order;
  unsigned long long* root64 = (unsigned long long*)root;
  unsigned short curD = onbr[lane];
  int4 curI = ord4[0];
  const int NG = NPTS / 4;
  for (int grp = 0; grp < NG; ++grp) {
    unsigned short nxtD = 0;
    int4 nxtI = make_int4(0, 0, 0, 0);
    if (grp + 1 < NG) {
      nxtD = onbr[(grp + 1) * 64 + lane];
      nxtI = ord4[grp + 1];
    }
    const int di = curD;
    const int nbr = di & 0x1FFF;
    const bool valid = (di & 0x8000) != 0;
    const int iMine = (sg == 0) ? curI.x : (sg == 1) ? curI.y : (sg == 2) ? curI.z : curI.w;
    const int rd = root[nbr];           // single-hop find (invariant)
    const unsigned long long vbAll = __ballot(valid);
    const unsigned long long vb0 = vbAll & 0xFFFFull;
    const unsigned long long vb1 = (vbAll >> 16) & 0xFFFFull;
    const unsigned long long vb2 = (vbAll >> 32) & 0xFFFFull;
    const unsigned long long vb3 = (vbAll >> 48) & 0xFFFFull;
    const int gc0 = vb0 ? __builtin_amdgcn_readlane(rd, __ffsll(vb0) - 1) : curI.x;
    const int gc1 = vb1 ? __builtin_amdgcn_readlane(rd, 16 + __ffsll(vb1) - 1) : curI.y;
    const int gc2 = vb2 ? __builtin_amdgcn_readlane(rd, 32 + __ffsll(vb2) - 1) : curI.z;
    const int gc3 = vb3 ? __builtin_amdgcn_readlane(rd, 48 + __ffsll(vb3) - 1) : curI.w;
    const int gcMine = (sg == 0) ? gc0 : (sg == 1) ? gc1 : (sg == 2) ? gc2 : gc3;
    const bool uniOk = !valid || (rd == gcMine);
    const bool collide =
        valid && (rd == curI.x || rd == curI.y || rd == curI.z || rd == curI.w);
    if (__all(uniOk && !collide)) {
      if ((lane & 15) == 0) root[iMine] = (unsigned short)gcMine;
    } else {
#pragma unroll
      for (int s = 0; s < 4; ++s) {
        const unsigned long long smask = 0xFFFFull << (16 * s);
        const int rc = (s == 0) ? rd : (int)root[nbr];
        unsigned long long vb = vbAll & smask;
        if (vb != 0) {
          int cl = __ffsll(vb) - 1;
          int gc = __builtin_amdgcn_readlane(rc, cl);
          unsigned long long uni = __ballot(!valid || rc == gc) & smask;
          if (uni == smask) {
            if (lane == 16 * s) root[iMine] = (unsigned short)gc;
          } else {
            float kr = valid ? kdeS[rc] : -1.0f;
            float mx = kr;
#pragma unroll
            for (int mk = 1; mk <= 8; mk <<= 1) mx = fmaxf(mx, __shfl_xor(mx, mk, 64));
            unsigned long long b = __ballot(valid && kr == mx) & smask;
            int kwin = __ffsll(b) - 1;
            int g = __builtin_amdgcn_readlane(rc, kwin);
            bool dying = (sg == s) && valid && (rc != g);
            if (dying) {
              root[rc] = (unsigned short)g;
              death[rc] = iMine;
            }
            if (lane == 16 * s) root[iMine] = (unsigned short)g;
#pragma unroll 1
            for (int it = 0; it < NPTS / 256; ++it) {
              int idx = it * 64 + lane;
              unsigned long long wv = root64[idx];
              unsigned e0 = (unsigned)(wv & 0xFFFFull);
              unsigned e1 = (unsigned)((wv >> 16) & 0xFFFFull);
              unsigned e2 = (unsigned)((wv >> 32) & 0xFFFFull);
              unsigned e3 = (unsigned)((wv >> 48) & 0xFFFFull);
              e0 = root[e0]; e1 = root[e1]; e2 = root[e2]; e3 = root[e3];
              root64[idx] = (unsigned long long)e0 | ((unsigned long long)e1 << 16) |
                            ((unsigned long long)e2 << 32) | ((unsigned long long)e3 << 48);
            }
          }
        }
      }
    }
    curD = nxtD;
    curI = nxtI;
  }
  if (lane == 0) death[order[0]] = scali[0];  // essential pair
}

// ---------------- loss: top-10 persistence, l_change + l_salient (f32 out) ----------------
__global__ __launch_bounds__(256) void loss_kernel(const float* __restrict__ kde,
                                                   const int* __restrict__ death,
                                                   float* __restrict__ out) {
  __shared__ float redv[256];
  __shared__ int redi[256];
  const int t = threadIdx.x;
  int chosen[DESTNUM];
  for (int k = 0; k < DESTNUM; ++k) {
    float bv = -__builtin_inff();
    int bi = 1 << 30;
    for (int p = t; p < NPTS; p += 256) {
      int d = death[p];
      if (d < 0) continue;
      bool used = false;
      for (int c = 0; c < k; ++c) used |= (chosen[c] == p);
      if (used) continue;
      float pers = kde[p] - kde[d];
      if (pers > bv || (pers == bv && p < bi)) { bv = pers; bi = p; }
    }
    redv[t] = bv; redi[t] = bi;
    __syncthreads();
    for (int s = 128; s; s >>= 1) {
      if (t < s) {
        if (redv[t + s] > redv[t] || (redv[t + s] == redv[t] && redi[t + s] < redi[t])) {
          redv[t] = redv[t + s];
          redi[t] = redi[t + s];
        }
      }
      __syncthreads();
    }
    chosen[k] = redi[0];
    __syncthreads();
  }
  float acc = 0.f;
  for (int p = t; p < NPTS; p += 256) {
    int d = death[p];
    if (d < 0) continue;
    bool sal = false;
    for (int c = 0; c < DESTNUM; ++c) sal |= (chosen[c] == p);
    float dv = kde[d];
    float kp = kde[p];
    acc += sal ? ((kp - 1.f) * (kp - 1.f) + dv * dv) : (kp - dv) * (kp - dv);
  }
  redv[t] = acc;
  __syncthreads();
  for (int s = 128; s; s >>= 1) {
    if (t < s) redv[t] += redv[t + s];
    __syncthreads();
  }
  if (t == 0) out[0] = redv[0];
}

extern "C" void kernel_launch(void* const* d_in, const int* in_sizes, int n_in,
                              void* d_out, int out_size, void* d_ws, size_t ws_size,
                              hipStream_t stream) {
  const unsigned short* x = (const unsigned short*)d_in[0];

  float* kde = (float*)d_ws;                      // NPTS f32
  float* scalf = kde + NPTS;                      // [0] = kdemax
  int* scali = (int*)(scalf + 64);                // [0] = argmin idx
  int* flag = scali + 64;                         // [0] = dtype flag (1=bf16, 0=f32)
  float* sqv = (float*)(flag + 64);               // NPTS squared norms
  int* order = (int*)(sqv + NPTS);                // NPTS (16B-aligned for int4 loads)
  int* rankp = order + NPTS;                      // NPTS
  int* rips = rankp + NPTS;                       // NPTS*KRIPS
  unsigned short* onbr = (unsigned short*)(rips + NPTS * KRIPS);  // NPTS*KRIPS u16
  int* death = (int*)(onbr + NPTS * KRIPS);       // NPTS

  hipLaunchKernelGGL(detect_kernel, dim3(1), dim3(64), 0, stream, x, flag);
  hipLaunchKernelGGL(sq_kernel, dim3(NPTS / 256), dim3(256), 0, stream, x, flag, sqv);
  hipLaunchKernelGGL(knn_kernel, dim3(NPTS), dim3(256), 0, stream, x, flag, sqv, kde, rips);
  hipLaunchKernelGGL(max_kernel, dim3(1), dim3(256), 0, stream, kde, scalf);
  hipLaunchKernelGGL(norm_kernel, dim3(NPTS / 256), dim3(256), 0, stream, kde, scalf, death);
  hipLaunchKernelGGL(argmin_kernel, dim3(1), dim3(256), 0, stream, kde, scali);
  hipLaunchKernelGGL(sort_kernel, dim3(1), dim3(256), 0, stream, kde, order, rankp);
  hipLaunchKernelGGL(onbr_kernel, dim3(NPTS * KRIPS / 256), dim3(256), 0, stream,
                     order, rankp, rips, onbr);
  hipLaunchKernelGGL(scan_kernel, dim3(1), dim3(64), 0, stream, kde, order, onbr, death, scali);
  hipLaunchKernelGGL(loss_kernel, dim3(1), dim3(256), 0, stream, kde, death, (float*)d_out);
}

// Round 12
// 2421.928 us; speedup vs baseline: 3.0839x; 2.0186x over previous
//
#include <hip/hip_runtime.h>
#include <hip/hip_bf16.h>

#define NPTS 8192
#define DIM 32
#define KKDE 32
#define KRIPS 16
#define DESTNUM 10

__device__ __forceinline__ unsigned long long shfl_xor_u64(unsigned long long v, int m) {
  int lo = __shfl_xor((int)(unsigned)(v & 0xFFFFFFFFull), m, 64);
  int hi = __shfl_xor((int)(unsigned)(v >> 32), m, 64);
  return (((unsigned long long)(unsigned)hi) << 32) | (unsigned)lo;
}

// ---------------- dtype detector: is x bf16-packed or f32? ----------------
__global__ __launch_bounds__(64) void detect_kernel(const unsigned short* __restrict__ x,
                                                    int* __restrict__ flag) {
  int lane = threadIdx.x;
  unsigned u = x[2 * lane];
  int e = (u >> 7) & 0xFF;
  bool pass = (e >= 110 && e <= 130);
  unsigned long long b = __ballot(pass);
  if (lane == 0) flag[0] = (__popcll(b) >= 32) ? 1 : 0;
}

// ---------------- kNN v3: R9 LDS-row compute (proven, no spill) + R11 bracket select ----------------
// One block per row i. d2 written to LDS exactly as R9 (bitwise-identical chains,
// diag cancels to exact 0). Selection: each wave brackets its own 2048 row values
// via binary search on value bits reading float4s from LDS (no barriers), compacts
// <=64 candidates, in-wave bitonic sorts (ties -> lower j, == jax top_k), then two
// merge rounds give the global ascending top-32.
__global__ __launch_bounds__(256) void knn_kernel(const unsigned short* __restrict__ xh,
                                                  const int* __restrict__ flag,
                                                  float* __restrict__ kde,
                                                  int* __restrict__ rips) {
  __shared__ float row[NPTS];                  // 32 KB
  __shared__ int cnt[4];
  __shared__ unsigned long long cand[4 * 64];  // 2 KB
  __shared__ unsigned long long srt[4 * 32];   // 1 KB
  __shared__ unsigned long long fin[64];       // 512 B
  __shared__ float knnv[KKDE];
  __shared__ int knni[KKDE];
  __shared__ float xis[DIM];
  __shared__ int flagS;
  const int i = blockIdx.x;
  const int t = threadIdx.x;
  const int w = t >> 6, lane = t & 63;
  if (t == 0) flagS = flag[0];
  __syncthreads();
  const bool isbf16 = (flagS != 0);
  const float* xf = (const float*)xh;
  if (t < DIM)
    xis[t] = isbf16 ? __uint_as_float(((unsigned)xh[i * DIM + t]) << 16)
                    : xf[i * DIM + t];
  __syncthreads();
  float xi[DIM];
#pragma unroll
  for (int q = 0; q < DIM; ++q) xi[q] = xis[q];
  float sqi = 0.f;
#pragma unroll
  for (int q = 0; q < DIM; ++q) sqi = fmaf(xi[q], xi[q], sqi);
  // ---- compute phase (R9 verbatim): d2 row into LDS ----
  for (int j = t; j < NPTS; j += 256) {
    float xr[DIM];
    if (isbf16) {
      const uint4* xj = (const uint4*)(xh + j * DIM);
#pragma unroll
      for (int q = 0; q < DIM / 8; ++q) {
        uint4 wv = xj[q];
        xr[q * 8 + 0] = __uint_as_float(wv.x << 16);
        xr[q * 8 + 1] = __uint_as_float(wv.x & 0xFFFF0000u);
        xr[q * 8 + 2] = __uint_as_float(wv.y << 16);
        xr[q * 8 + 3] = __uint_as_float(wv.y & 0xFFFF0000u);
        xr[q * 8 + 4] = __uint_as_float(wv.z << 16);
        xr[q * 8 + 5] = __uint_as_float(wv.z & 0xFFFF0000u);
        xr[q * 8 + 6] = __uint_as_float(wv.w << 16);
        xr[q * 8 + 7] = __uint_as_float(wv.w & 0xFFFF0000u);
      }
    } else {
      const float4* xj = (const float4*)(xf + j * DIM);
#pragma unroll
      for (int q = 0; q < DIM / 4; ++q) {
        float4 wv = xj[q];
        xr[q * 4 + 0] = wv.x; xr[q * 4 + 1] = wv.y;
        xr[q * 4 + 2] = wv.z; xr[q * 4 + 3] = wv.w;
      }
    }
    float dot = 0.f, sqj = 0.f;
#pragma unroll
    for (int q = 0; q < DIM; ++q) {
      dot = fmaf(xi[q], xr[q], dot);
      sqj = fmaf(xr[q], xr[q], sqj);
    }
    // j==i: dot==sqi==sqj bitwise (identical chains) -> fmaf(-2,s,2s) == 0 exactly
    row[j] = fmaxf(fmaf(-2.f, dot, sqi + sqj), 0.f);
  }
  __syncthreads();
  // ---- per-wave bracket: smallest T with count(<=T) >= 32 (count <= 64) ----
  // wave w owns row[w*2048 .. w*2048+2047]; d2 >= +0 so uint compare == float compare
  const float4* rowf4 = (const float4*)row;
  unsigned lo = 0u, hi = 0x7F800000u;
  int chi = 2048;
  while (chi > 64 && (hi - lo) > 1u) {
    const unsigned mid = lo + ((hi - lo) >> 1);
    int c = 0;
#pragma unroll
    for (int s = 0; s < 8; ++s) {
      float4 v = rowf4[(w << 9) + (s << 6) + lane];
      c += (__float_as_uint(v.x) <= mid) ? 1 : 0;
      c += (__float_as_uint(v.y) <= mid) ? 1 : 0;
      c += (__float_as_uint(v.z) <= mid) ? 1 : 0;
      c += (__float_as_uint(v.w) <= mid) ? 1 : 0;
    }
#pragma unroll
    for (int m = 1; m <= 32; m <<= 1) c += __shfl_xor(c, m, 64);
    if (c >= 32) { hi = mid; chi = c; } else { lo = mid; }
  }
  // ---- compact candidates (per-wave LDS region; same-wave ops are ordered) ----
  if (lane == 0) cnt[w] = 0;
  cand[(w << 6) | lane] = ~0ull;
#pragma unroll
  for (int s = 0; s < 8; ++s) {
    const int fidx = (w << 9) + (s << 6) + lane;
    float4 v = rowf4[fidx];
    const unsigned b0 = __float_as_uint(v.x), b1 = __float_as_uint(v.y);
    const unsigned b2 = __float_as_uint(v.z), b3 = __float_as_uint(v.w);
    if (b0 <= hi) {
      int pos = atomicAdd(&cnt[w], 1);
      if (pos < 64) cand[(w << 6) + pos] = (((unsigned long long)b0) << 32) | (unsigned)(fidx * 4 + 0);
    }
    if (b1 <= hi) {
      int pos = atomicAdd(&cnt[w], 1);
      if (pos < 64) cand[(w << 6) + pos] = (((unsigned long long)b1) << 32) | (unsigned)(fidx * 4 + 1);
    }
    if (b2 <= hi) {
      int pos = atomicAdd(&cnt[w], 1);
      if (pos < 64) cand[(w << 6) + pos] = (((unsigned long long)b2) << 32) | (unsigned)(fidx * 4 + 2);
    }
    if (b3 <= hi) {
      int pos = atomicAdd(&cnt[w], 1);
      if (pos < 64) cand[(w << 6) + pos] = (((unsigned long long)b3) << 32) | (unsigned)(fidx * 4 + 3);
    }
  }
  // ---- in-wave bitonic sort of 64 keys (R11 proven) ----
  unsigned long long v = cand[(w << 6) | lane];
#pragma unroll
  for (int k = 2; k <= 64; k <<= 1) {
#pragma unroll
    for (int j = 32; j > 0; j >>= 1) {
      if (j >= k) continue;
      unsigned long long o = shfl_xor_u64(v, j);
      bool keepMin = (((lane & k) == 0) == ((lane & j) == 0));
      v = keepMin ? (v < o ? v : o) : (v > o ? v : o);
    }
  }
  if (lane < 32) srt[(w << 5) | lane] = v;
  __syncthreads();
  // ---- merge round 1: (w0: lists 0,1) (w1: lists 2,3) ----
  if (w < 2) {
    const unsigned long long* A = &srt[(w * 2) << 5];
    const unsigned long long* B = &srt[(w * 2 + 1) << 5];
    unsigned long long m = (lane < 32) ? A[lane] : B[63 - lane];
#pragma unroll
    for (int j = 32; j > 0; j >>= 1) {
      unsigned long long o = shfl_xor_u64(m, j);
      bool keepMin = ((lane & j) == 0);
      m = keepMin ? (m < o ? m : o) : (m > o ? m : o);
    }
    if (lane < 32) fin[(w << 5) | lane] = m;
  }
  __syncthreads();
  // ---- merge round 2: wave0 merges the two 32-lists -> final ascending 32 ----
  if (w == 0) {
    unsigned long long m = (lane < 32) ? fin[lane] : fin[32 + (63 - lane)];
#pragma unroll
    for (int j = 32; j > 0; j >>= 1) {
      unsigned long long o = shfl_xor_u64(m, j);
      bool keepMin = ((lane & j) == 0);
      m = keepMin ? (m < o ? m : o) : (m > o ? m : o);
    }
    if (lane < 32) {
      knnv[lane] = __uint_as_float((unsigned)(m >> 32));
      knni[lane] = (int)(m & 0x1FFFull);
    }
  }
  __syncthreads();
  if (t == 0) {
    float s = 0.f;
    for (int k = 0; k < KKDE; ++k) s += expf(knnv[k] * -0.015625f);  // exp(-d2/64), ascending
    kde[i] = s;
  }
  if (t < KRIPS) rips[i * KRIPS + t] = knni[t];
}

// ---------------- max(kde) ----------------
__global__ __launch_bounds__(256) void max_kernel(const float* __restrict__ kde,
                                                  float* __restrict__ scalf) {
  __shared__ float red[256];
  int t = threadIdx.x;
  float m = 0.f;
  for (int p = t; p < NPTS; p += 256) m = fmaxf(m, kde[p]);
  red[t] = m;
  __syncthreads();
  for (int s = 128; s; s >>= 1) {
    if (t < s) red[t] = fmaxf(red[t], red[t + s]);
    __syncthreads();
  }
  if (t == 0) scalf[0] = red[0];
}

// ---------------- normalize + init death ----------------
__global__ __launch_bounds__(256) void norm_kernel(float* __restrict__ kde,
                                                   const float* __restrict__ scalf,
                                                   int* __restrict__ death) {
  int p = blockIdx.x * 256 + threadIdx.x;
  if (p < NPTS) {
    kde[p] = kde[p] / scalf[0];
    death[p] = -1;
  }
}

// ---------------- argmin(kde) ----------------
__global__ __launch_bounds__(256) void argmin_kernel(const float* __restrict__ kde,
                                                     int* __restrict__ scali) {
  __shared__ unsigned long long red[256];
  int t = threadIdx.x;
  unsigned long long best = ~0ull;
  for (int p = t; p < NPTS; p += 256) {
    unsigned long long kk = (((unsigned long long)__float_as_uint(kde[p])) << 32) | (unsigned)p;
    if (kk < best) best = kk;
  }
  red[t] = best;
  __syncthreads();
  for (int s = 128; s; s >>= 1) {
    if (t < s && red[t + s] < red[t]) red[t] = red[t + s];
    __syncthreads();
  }
  if (t == 0) scali[0] = (int)(red[0] & 0xFFFFFFFFull);
}

// ---------------- bitonic sort: order = argsort(-kde) (stable), rank = inverse ----------------
__global__ __launch_bounds__(256) void sort_kernel(const float* __restrict__ kde,
                                                   int* __restrict__ order,
                                                   int* __restrict__ rankp) {
  __shared__ float kv[NPTS];            // 32 KB
  __shared__ unsigned short ki[NPTS];   // 16 KB
  int t = threadIdx.x;
  for (int p = t; p < NPTS; p += 256) { kv[p] = kde[p]; ki[p] = (unsigned short)p; }
  __syncthreads();
  for (int size = 2; size <= NPTS; size <<= 1) {
    for (int stride = size >> 1; stride > 0; stride >>= 1) {
      for (int q = t; q < NPTS / 2; q += 256) {
        int lo = ((q & ~(stride - 1)) << 1) | (q & (stride - 1));
        int hi = lo + stride;
        float va = kv[lo], vb = kv[hi];
        int ia = ki[lo], ib = ki[hi];
        bool aFirst = (va > vb) || (va == vb && ia < ib);
        bool up = ((lo & size) == 0);
        if (up != aFirst) {
          kv[lo] = vb; kv[hi] = va;
          ki[lo] = (unsigned short)ib; ki[hi] = (unsigned short)ia;
        }
      }
      __syncthreads();
    }
  }
  for (int p = t; p < NPTS; p += 256) {
    int idx = ki[p];
    order[p] = idx;
    rankp[idx] = p;
  }
}

// ---------------- ordered neighbor stream (flat: [t*16 + kk]) ----------------
__global__ __launch_bounds__(256) void onbr_kernel(const int* __restrict__ order,
                                                   const int* __restrict__ rankp,
                                                   const int* __restrict__ rips,
                                                   unsigned short* __restrict__ onbr) {
  int e = blockIdx.x * 256 + threadIdx.x;  // e < NPTS*KRIPS
  if (e >= NPTS * KRIPS) return;
  int t = e >> 4, kk = e & 15;
  int i = order[t];
  int nbr = rips[i * KRIPS + kk];
  bool valid = rankp[nbr] < t;  // self has rank == t -> invalid, matching ref
  onbr[e] = (unsigned short)(nbr | (valid ? 0x8000 : 0));
}

// ---------------- persistence scan: eagerly-compressed union-find (R9, proven) ----------------
__global__ __launch_bounds__(64) void scan_kernel(const float* __restrict__ kde,
                                                  const int* __restrict__ order,
                                                  const unsigned short* __restrict__ onbr,
                                                  int* __restrict__ death,
                                                  const int* __restrict__ scali) {
  __shared__ float kdeS[NPTS];          // 32 KB
  __shared__ unsigned short root[NPTS]; // 16 KB
  const int lane = threadIdx.x;
  for (int p = lane; p < NPTS; p += 64) { kdeS[p] = kde[p]; root[p] = (unsigned short)p; }
  __syncthreads();
  const int sg = lane >> 4;
  const int4* ord4 = (const int4*)order;
  unsigned long long* root64 = (unsigned long long*)root;
  unsigned short curD = onbr[lane];
  int4 curI = ord4[0];
  const int NG = NPTS / 4;
  for (int grp = 0; grp < NG; ++grp) {
    unsigned short nxtD = 0;
    int4 nxtI = make_int4(0, 0, 0, 0);
    if (grp + 1 < NG) {
      nxtD = onbr[(grp + 1) * 64 + lane];
      nxtI = ord4[grp + 1];
    }
    const int di = curD;
    const int nbr = di & 0x1FFF;
    const bool valid = (di & 0x8000) != 0;
    const int iMine = (sg == 0) ? curI.x : (sg == 1) ? curI.y : (sg == 2) ? curI.z : curI.w;
    const int rd = root[nbr];           // single-hop find (invariant)
    const unsigned long long vbAll = __ballot(valid);
    const unsigned long long vb0 = vbAll & 0xFFFFull;
    const unsigned long long vb1 = (vbAll >> 16) & 0xFFFFull;
    const unsigned long long vb2 = (vbAll >> 32) & 0xFFFFull;
    const unsigned long long vb3 = (vbAll >> 48) & 0xFFFFull;
    const int gc0 = vb0 ? __builtin_amdgcn_readlane(rd, __ffsll(vb0) - 1) : curI.x;
    const int gc1 = vb1 ? __builtin_amdgcn_readlane(rd, 16 + __ffsll(vb1) - 1) : curI.y;
    const int gc2 = vb2 ? __builtin_amdgcn_readlane(rd, 32 + __ffsll(vb2) - 1) : curI.z;
    const int gc3 = vb3 ? __builtin_amdgcn_readlane(rd, 48 + __ffsll(vb3) - 1) : curI.w;
    const int gcMine = (sg == 0) ? gc0 : (sg == 1) ? gc1 : (sg == 2) ? gc2 : gc3;
    const bool uniOk = !valid || (rd == gcMine);
    const bool collide =
        valid && (rd == curI.x || rd == curI.y || rd == curI.z || rd == curI.w);
    if (__all(uniOk && !collide)) {
      if ((lane & 15) == 0) root[iMine] = (unsigned short)gcMine;
    } else {
#pragma unroll
      for (int s = 0; s < 4; ++s) {
        const unsigned long long smask = 0xFFFFull << (16 * s);
        const int rc = (s == 0) ? rd : (int)root[nbr];
        unsigned long long vb = vbAll & smask;
        if (vb != 0) {
          int cl = __ffsll(vb) - 1;
          int gc = __builtin_amdgcn_readlane(rc, cl);
          unsigned long long uni = __ballot(!valid || rc == gc) & smask;
          if (uni == smask) {
            if (lane == 16 * s) root[iMine] = (unsigned short)gc;
          } else {
            float kr = valid ? kdeS[rc] : -1.0f;
            float mx = kr;
#pragma unroll
            for (int mk = 1; mk <= 8; mk <<= 1) mx = fmaxf(mx, __shfl_xor(mx, mk, 64));
            unsigned long long b = __ballot(valid && kr == mx) & smask;
            int kwin = __ffsll(b) - 1;
            int g = __builtin_amdgcn_readlane(rc, kwin);
            bool dying = (sg == s) && valid && (rc != g);
            if (dying) {
              root[rc] = (unsigned short)g;
              death[rc] = iMine;
            }
            if (lane == 16 * s) root[iMine] = (unsigned short)g;
#pragma unroll 1
            for (int it = 0; it < NPTS / 256; ++it) {
              int idx = it * 64 + lane;
              unsigned long long wv = root64[idx];
              unsigned e0 = (unsigned)(wv & 0xFFFFull);
              unsigned e1 = (unsigned)((wv >> 16) & 0xFFFFull);
              unsigned e2 = (unsigned)((wv >> 32) & 0xFFFFull);
              unsigned e3 = (unsigned)((wv >> 48) & 0xFFFFull);
              e0 = root[e0]; e1 = root[e1]; e2 = root[e2]; e3 = root[e3];
              root64[idx] = (unsigned long long)e0 | ((unsigned long long)e1 << 16) |
                            ((unsigned long long)e2 << 32) | ((unsigned long long)e3 << 48);
            }
          }
        }
      }
    }
    curD = nxtD;
    curI = nxtI;
  }
  if (lane == 0) death[order[0]] = scali[0];  // essential pair
}

// ---------------- loss: top-10 persistence, l_change + l_salient (f32 out) ----------------
__global__ __launch_bounds__(256) void loss_kernel(const float* __restrict__ kde,
                                                   const int* __restrict__ death,
                                                   float* __restrict__ out) {
  __shared__ float redv[256];
  __shared__ int redi[256];
  const int t = threadIdx.x;
  int chosen[DESTNUM];
  for (int k = 0; k < DESTNUM; ++k) {
    float bv = -__builtin_inff();
    int bi = 1 << 30;
    for (int p = t; p < NPTS; p += 256) {
      int d = death[p];
      if (d < 0) continue;
      bool used = false;
      for (int c = 0; c < k; ++c) used |= (chosen[c] == p);
      if (used) continue;
      float pers = kde[p] - kde[d];
      if (pers > bv || (pers == bv && p < bi)) { bv = pers; bi = p; }
    }
    redv[t] = bv; redi[t] = bi;
    __syncthreads();
    for (int s = 128; s; s >>= 1) {
      if (t < s) {
        if (redv[t + s] > redv[t] || (redv[t + s] == redv[t] && redi[t + s] < redi[t])) {
          redv[t] = redv[t + s];
          redi[t] = redi[t + s];
        }
      }
      __syncthreads();
    }
    chosen[k] = redi[0];
    __syncthreads();
  }
  float acc = 0.f;
  for (int p = t; p < NPTS; p += 256) {
    int d = death[p];
    if (d < 0) continue;
    bool sal = false;
    for (int c = 0; c < DESTNUM; ++c) sal |= (chosen[c] == p);
    float dv = kde[d];
    float kp = kde[p];
    acc += sal ? ((kp - 1.f) * (kp - 1.f) + dv * dv) : (kp - dv) * (kp - dv);
  }
  redv[t] = acc;
  __syncthreads();
  for (int s = 128; s; s >>= 1) {
    if (t < s) redv[t] += redv[t + s];
    __syncthreads();
  }
  if (t == 0) out[0] = redv[0];
}

extern "C" void kernel_launch(void* const* d_in, const int* in_sizes, int n_in,
                              void* d_out, int out_size, void* d_ws, size_t ws_size,
                              hipStream_t stream) {
  const unsigned short* x = (const unsigned short*)d_in[0];

  float* kde = (float*)d_ws;                      // NPTS f32
  float* scalf = kde + NPTS;                      // [0] = kdemax
  int* scali = (int*)(scalf + 64);                // [0] = argmin idx
  int* flag = scali + 64;                         // [0] = dtype flag (1=bf16, 0=f32)
  int* order = flag + 64;                         // NPTS (16B-aligned for int4 loads)
  int* rankp = order + NPTS;                      // NPTS
  int* rips = rankp + NPTS;                       // NPTS*KRIPS
  unsigned short* onbr = (unsigned short*)(rips + NPTS * KRIPS);  // NPTS*KRIPS u16
  int* death = (int*)(onbr + NPTS * KRIPS);       // NPTS

  hipLaunchKernelGGL(detect_kernel, dim3(1), dim3(64), 0, stream, x, flag);
  hipLaunchKernelGGL(knn_kernel, dim3(NPTS), dim3(256), 0, stream, x, flag, kde, rips);
  hipLaunchKernelGGL(max_kernel, dim3(1), dim3(256), 0, stream, kde, scalf);
  hipLaunchKernelGGL(norm_kernel, dim3(NPTS / 256), dim3(256), 0, stream, kde, scalf, death);
  hipLaunchKernelGGL(argmin_kernel, dim3(1), dim3(256), 0, stream, kde, scali);
  hipLaunchKernelGGL(sort_kernel, dim3(1), dim3(256), 0, stream, kde, order, rankp);
  hipLaunchKernelGGL(onbr_kernel, dim3(NPTS * KRIPS / 256), dim3(256), 0, stream,
                     order, rankp, rips, onbr);
  hipLaunchKernelGGL(scan_kernel, dim3(1), dim3(64), 0, stream, kde, order, onbr, death, scali);
  hipLaunchKernelGGL(loss_kernel, dim3(1), dim3(256), 0, stream, kde, death, (float*)d_out);
}

// Round 13
// 2055.701 us; speedup vs baseline: 3.6334x; 1.1782x over previous
//
#include <hip/hip_runtime.h>
#include <hip/hip_bf16.h>

#define NPTS 8192
#define DIM 32
#define KKDE 32
#define KRIPS 16
#define DESTNUM 10

__device__ __forceinline__ unsigned long long shfl_xor_u64(unsigned long long v, int m) {
  int lo = __shfl_xor((int)(unsigned)(v & 0xFFFFFFFFull), m, 64);
  int hi = __shfl_xor((int)(unsigned)(v >> 32), m, 64);
  return (((unsigned long long)(unsigned)hi) << 32) | (unsigned)lo;
}

// ---------------- dtype detector: is x bf16-packed or f32? ----------------
__global__ __launch_bounds__(64) void detect_kernel(const unsigned short* __restrict__ x,
                                                    int* __restrict__ flag) {
  int lane = threadIdx.x;
  unsigned u = x[2 * lane];
  int e = (u >> 7) & 0xFF;
  bool pass = (e >= 110 && e <= 130);
  unsigned long long b = __ballot(pass);
  if (lane == 0) flag[0] = (__popcll(b) >= 32) ? 1 : 0;
}

// ---------------- kNN v3 (R12 proven): LDS-row compute + per-wave bracket select ----------------
__global__ __launch_bounds__(256) void knn_kernel(const unsigned short* __restrict__ xh,
                                                  const int* __restrict__ flag,
                                                  float* __restrict__ kde,
                                                  int* __restrict__ rips) {
  __shared__ float row[NPTS];                  // 32 KB
  __shared__ int cnt[4];
  __shared__ unsigned long long cand[4 * 64];  // 2 KB
  __shared__ unsigned long long srt[4 * 32];   // 1 KB
  __shared__ unsigned long long fin[64];       // 512 B
  __shared__ float knnv[KKDE];
  __shared__ int knni[KKDE];
  __shared__ float xis[DIM];
  __shared__ int flagS;
  const int i = blockIdx.x;
  const int t = threadIdx.x;
  const int w = t >> 6, lane = t & 63;
  if (t == 0) flagS = flag[0];
  __syncthreads();
  const bool isbf16 = (flagS != 0);
  const float* xf = (const float*)xh;
  if (t < DIM)
    xis[t] = isbf16 ? __uint_as_float(((unsigned)xh[i * DIM + t]) << 16)
                    : xf[i * DIM + t];
  __syncthreads();
  float xi[DIM];
#pragma unroll
  for (int q = 0; q < DIM; ++q) xi[q] = xis[q];
  float sqi = 0.f;
#pragma unroll
  for (int q = 0; q < DIM; ++q) sqi = fmaf(xi[q], xi[q], sqi);
  // ---- compute phase: d2 row into LDS ----
  for (int j = t; j < NPTS; j += 256) {
    float xr[DIM];
    if (isbf16) {
      const uint4* xj = (const uint4*)(xh + j * DIM);
#pragma unroll
      for (int q = 0; q < DIM / 8; ++q) {
        uint4 wv = xj[q];
        xr[q * 8 + 0] = __uint_as_float(wv.x << 16);
        xr[q * 8 + 1] = __uint_as_float(wv.x & 0xFFFF0000u);
        xr[q * 8 + 2] = __uint_as_float(wv.y << 16);
        xr[q * 8 + 3] = __uint_as_float(wv.y & 0xFFFF0000u);
        xr[q * 8 + 4] = __uint_as_float(wv.z << 16);
        xr[q * 8 + 5] = __uint_as_float(wv.z & 0xFFFF0000u);
        xr[q * 8 + 6] = __uint_as_float(wv.w << 16);
        xr[q * 8 + 7] = __uint_as_float(wv.w & 0xFFFF0000u);
      }
    } else {
      const float4* xj = (const float4*)(xf + j * DIM);
#pragma unroll
      for (int q = 0; q < DIM / 4; ++q) {
        float4 wv = xj[q];
        xr[q * 4 + 0] = wv.x; xr[q * 4 + 1] = wv.y;
        xr[q * 4 + 2] = wv.z; xr[q * 4 + 3] = wv.w;
      }
    }
    float dot = 0.f, sqj = 0.f;
#pragma unroll
    for (int q = 0; q < DIM; ++q) {
      dot = fmaf(xi[q], xr[q], dot);
      sqj = fmaf(xr[q], xr[q], sqj);
    }
    // j==i: dot==sqi==sqj bitwise (identical chains) -> fmaf(-2,s,2s) == 0 exactly
    row[j] = fmaxf(fmaf(-2.f, dot, sqi + sqj), 0.f);
  }
  __syncthreads();
  // ---- per-wave bracket: smallest T with count(<=T) >= 32 (count <= 64) ----
  const float4* rowf4 = (const float4*)row;
  unsigned lo = 0u, hi = 0x7F800000u;
  int chi = 2048;
  while (chi > 64 && (hi - lo) > 1u) {
    const unsigned mid = lo + ((hi - lo) >> 1);
    int c = 0;
#pragma unroll
    for (int s = 0; s < 8; ++s) {
      float4 v = rowf4[(w << 9) + (s << 6) + lane];
      c += (__float_as_uint(v.x) <= mid) ? 1 : 0;
      c += (__float_as_uint(v.y) <= mid) ? 1 : 0;
      c += (__float_as_uint(v.z) <= mid) ? 1 : 0;
      c += (__float_as_uint(v.w) <= mid) ? 1 : 0;
    }
#pragma unroll
    for (int m = 1; m <= 32; m <<= 1) c += __shfl_xor(c, m, 64);
    if (c >= 32) { hi = mid; chi = c; } else { lo = mid; }
  }
  // ---- compact candidates ----
  if (lane == 0) cnt[w] = 0;
  cand[(w << 6) | lane] = ~0ull;
#pragma unroll
  for (int s = 0; s < 8; ++s) {
    const int fidx = (w << 9) + (s << 6) + lane;
    float4 v = rowf4[fidx];
    const unsigned b0 = __float_as_uint(v.x), b1 = __float_as_uint(v.y);
    const unsigned b2 = __float_as_uint(v.z), b3 = __float_as_uint(v.w);
    if (b0 <= hi) {
      int pos = atomicAdd(&cnt[w], 1);
      if (pos < 64) cand[(w << 6) + pos] = (((unsigned long long)b0) << 32) | (unsigned)(fidx * 4 + 0);
    }
    if (b1 <= hi) {
      int pos = atomicAdd(&cnt[w], 1);
      if (pos < 64) cand[(w << 6) + pos] = (((unsigned long long)b1) << 32) | (unsigned)(fidx * 4 + 1);
    }
    if (b2 <= hi) {
      int pos = atomicAdd(&cnt[w], 1);
      if (pos < 64) cand[(w << 6) + pos] = (((unsigned long long)b2) << 32) | (unsigned)(fidx * 4 + 2);
    }
    if (b3 <= hi) {
      int pos = atomicAdd(&cnt[w], 1);
      if (pos < 64) cand[(w << 6) + pos] = (((unsigned long long)b3) << 32) | (unsigned)(fidx * 4 + 3);
    }
  }
  // ---- in-wave bitonic sort of 64 keys ----
  unsigned long long v = cand[(w << 6) | lane];
#pragma unroll
  for (int k = 2; k <= 64; k <<= 1) {
#pragma unroll
    for (int j = 32; j > 0; j >>= 1) {
      if (j >= k) continue;
      unsigned long long o = shfl_xor_u64(v, j);
      bool keepMin = (((lane & k) == 0) == ((lane & j) == 0));
      v = keepMin ? (v < o ? v : o) : (v > o ? v : o);
    }
  }
  if (lane < 32) srt[(w << 5) | lane] = v;
  __syncthreads();
  // ---- merge round 1 ----
  if (w < 2) {
    const unsigned long long* A = &srt[(w * 2) << 5];
    const unsigned long long* B = &srt[(w * 2 + 1) << 5];
    unsigned long long m = (lane < 32) ? A[lane] : B[63 - lane];
#pragma unroll
    for (int j = 32; j > 0; j >>= 1) {
      unsigned long long o = shfl_xor_u64(m, j);
      bool keepMin = ((lane & j) == 0);
      m = keepMin ? (m < o ? m : o) : (m > o ? m : o);
    }
    if (lane < 32) fin[(w << 5) | lane] = m;
  }
  __syncthreads();
  // ---- merge round 2 ----
  if (w == 0) {
    unsigned long long m = (lane < 32) ? fin[lane] : fin[32 + (63 - lane)];
#pragma unroll
    for (int j = 32; j > 0; j >>= 1) {
      unsigned long long o = shfl_xor_u64(m, j);
      bool keepMin = ((lane & j) == 0);
      m = keepMin ? (m < o ? m : o) : (m > o ? m : o);
    }
    if (lane < 32) {
      knnv[lane] = __uint_as_float((unsigned)(m >> 32));
      knni[lane] = (int)(m & 0x1FFFull);
    }
  }
  __syncthreads();
  if (t == 0) {
    float s = 0.f;
    for (int k = 0; k < KKDE; ++k) s += expf(knnv[k] * -0.015625f);  // exp(-d2/64), ascending
    kde[i] = s;
  }
  if (t < KRIPS) rips[i * KRIPS + t] = knni[t];
}

// ---------------- max(kde) ----------------
__global__ __launch_bounds__(256) void max_kernel(const float* __restrict__ kde,
                                                  float* __restrict__ scalf) {
  __shared__ float red[256];
  int t = threadIdx.x;
  float m = 0.f;
  for (int p = t; p < NPTS; p += 256) m = fmaxf(m, kde[p]);
  red[t] = m;
  __syncthreads();
  for (int s = 128; s; s >>= 1) {
    if (t < s) red[t] = fmaxf(red[t], red[t + s]);
    __syncthreads();
  }
  if (t == 0) scalf[0] = red[0];
}

// ---------------- normalize + init death ----------------
__global__ __launch_bounds__(256) void norm_kernel(float* __restrict__ kde,
                                                   const float* __restrict__ scalf,
                                                   int* __restrict__ death) {
  int p = blockIdx.x * 256 + threadIdx.x;
  if (p < NPTS) {
    kde[p] = kde[p] / scalf[0];
    death[p] = -1;
  }
}

// ---------------- argmin(kde) ----------------
__global__ __launch_bounds__(256) void argmin_kernel(const float* __restrict__ kde,
                                                     int* __restrict__ scali) {
  __shared__ unsigned long long red[256];
  int t = threadIdx.x;
  unsigned long long best = ~0ull;
  for (int p = t; p < NPTS; p += 256) {
    unsigned long long kk = (((unsigned long long)__float_as_uint(kde[p])) << 32) | (unsigned)p;
    if (kk < best) best = kk;
  }
  red[t] = best;
  __syncthreads();
  for (int s = 128; s; s >>= 1) {
    if (t < s && red[t + s] < red[t]) red[t] = red[t + s];
    __syncthreads();
  }
  if (t == 0) scali[0] = (int)(red[0] & 0xFFFFFFFFull);
}

// ---------------- bitonic sort: order = argsort(-kde) (stable), rank = inverse ----------------
__global__ __launch_bounds__(256) void sort_kernel(const float* __restrict__ kde,
                                                   int* __restrict__ order,
                                                   int* __restrict__ rankp) {
  __shared__ float kv[NPTS];            // 32 KB
  __shared__ unsigned short ki[NPTS];   // 16 KB
  int t = threadIdx.x;
  for (int p = t; p < NPTS; p += 256) { kv[p] = kde[p]; ki[p] = (unsigned short)p; }
  __syncthreads();
  for (int size = 2; size <= NPTS; size <<= 1) {
    for (int stride = size >> 1; stride > 0; stride >>= 1) {
      for (int q = t; q < NPTS / 2; q += 256) {
        int lo = ((q & ~(stride - 1)) << 1) | (q & (stride - 1));
        int hi = lo + stride;
        float va = kv[lo], vb = kv[hi];
        int ia = ki[lo], ib = ki[hi];
        bool aFirst = (va > vb) || (va == vb && ia < ib);
        bool up = ((lo & size) == 0);
        if (up != aFirst) {
          kv[lo] = vb; kv[hi] = va;
          ki[lo] = (unsigned short)ib; ki[hi] = (unsigned short)ia;
        }
      }
      __syncthreads();
    }
  }
  for (int p = t; p < NPTS; p += 256) {
    int idx = ki[p];
    order[p] = idx;
    rankp[idx] = p;
  }
}

// ---------------- ordered neighbor stream (flat: [t*16 + kk]) ----------------
__global__ __launch_bounds__(256) void onbr_kernel(const int* __restrict__ order,
                                                   const int* __restrict__ rankp,
                                                   const int* __restrict__ rips,
                                                   unsigned short* __restrict__ onbr) {
  int e = blockIdx.x * 256 + threadIdx.x;  // e < NPTS*KRIPS
  if (e >= NPTS * KRIPS) return;
  int t = e >> 4, kk = e & 15;
  int i = order[t];
  int nbr = rips[i * KRIPS + kk];
  bool valid = rankp[nbr] < t;  // self has rank == t -> invalid, matching ref
  onbr[e] = (unsigned short)(nbr | (valid ? 0x8000 : 0));
}

// ---------------- persistence scan: eager union-find + prefetch-4 register ring ----------------
// Group body identical to R9 (absmax 0.0 x4 rounds). Global onbr/order loads are
// issued a full chunk (4 groups) ahead in constant-indexed registers, so the
// compiler's waitcnt finds the data landed instead of stalling ~L2 latency/group.
__global__ __launch_bounds__(64) void scan_kernel(const float* __restrict__ kde,
                                                  const int* __restrict__ order,
                                                  const unsigned short* __restrict__ onbr,
                                                  int* __restrict__ death,
                                                  const int* __restrict__ scali) {
  __shared__ float kdeS[NPTS];          // 32 KB
  __shared__ unsigned short root[NPTS]; // 16 KB
  const int lane = threadIdx.x;
  for (int p = lane; p < NPTS; p += 64) { kdeS[p] = kde[p]; root[p] = (unsigned short)p; }
  __syncthreads();
  const int sg = lane >> 4;
  const int4* ord4 = (const int4*)order;
  unsigned long long* root64 = (unsigned long long*)root;
  const int NG = NPTS / 4;

  auto process = [&](unsigned short cD, int4 cI) {
    const int di = cD;
    const int nbr = di & 0x1FFF;
    const bool valid = (di & 0x8000) != 0;
    const int iMine = (sg == 0) ? cI.x : (sg == 1) ? cI.y : (sg == 2) ? cI.z : cI.w;
    const int rd = root[nbr];           // single-hop find (invariant)
    const unsigned long long vbAll = __ballot(valid);
    const unsigned long long vb0 = vbAll & 0xFFFFull;
    const unsigned long long vb1 = (vbAll >> 16) & 0xFFFFull;
    const unsigned long long vb2 = (vbAll >> 32) & 0xFFFFull;
    const unsigned long long vb3 = (vbAll >> 48) & 0xFFFFull;
    const int gc0 = vb0 ? __builtin_amdgcn_readlane(rd, __ffsll(vb0) - 1) : cI.x;
    const int gc1 = vb1 ? __builtin_amdgcn_readlane(rd, 16 + __ffsll(vb1) - 1) : cI.y;
    const int gc2 = vb2 ? __builtin_amdgcn_readlane(rd, 32 + __ffsll(vb2) - 1) : cI.z;
    const int gc3 = vb3 ? __builtin_amdgcn_readlane(rd, 48 + __ffsll(vb3) - 1) : cI.w;
    const int gcMine = (sg == 0) ? gc0 : (sg == 1) ? gc1 : (sg == 2) ? gc2 : gc3;
    const bool uniOk = !valid || (rd == gcMine);
    const bool collide =
        valid && (rd == cI.x || rd == cI.y || rd == cI.z || rd == cI.w);
    if (__all(uniOk && !collide)) {
      if ((lane & 15) == 0) root[iMine] = (unsigned short)gcMine;
    } else {
#pragma unroll
      for (int s = 0; s < 4; ++s) {
        const unsigned long long smask = 0xFFFFull << (16 * s);
        const int rc = (s == 0) ? rd : (int)root[nbr];
        unsigned long long vb = vbAll & smask;
        if (vb != 0) {
          int cl = __ffsll(vb) - 1;
          int gc = __builtin_amdgcn_readlane(rc, cl);
          unsigned long long uni = __ballot(!valid || rc == gc) & smask;
          if (uni == smask) {
            if (lane == 16 * s) root[iMine] = (unsigned short)gc;
          } else {
            float kr = valid ? kdeS[rc] : -1.0f;
            float mx = kr;
#pragma unroll
            for (int mk = 1; mk <= 8; mk <<= 1) mx = fmaxf(mx, __shfl_xor(mx, mk, 64));
            unsigned long long b = __ballot(valid && kr == mx) & smask;
            int kwin = __ffsll(b) - 1;
            int g = __builtin_amdgcn_readlane(rc, kwin);
            bool dying = (sg == s) && valid && (rc != g);
            if (dying) {
              root[rc] = (unsigned short)g;
              death[rc] = iMine;
            }
            if (lane == 16 * s) root[iMine] = (unsigned short)g;
#pragma unroll 1
            for (int it = 0; it < NPTS / 256; ++it) {
              int idx = it * 64 + lane;
              unsigned long long wv = root64[idx];
              unsigned e0 = (unsigned)(wv & 0xFFFFull);
              unsigned e1 = (unsigned)((wv >> 16) & 0xFFFFull);
              unsigned e2 = (unsigned)((wv >> 32) & 0xFFFFull);
              unsigned e3 = (unsigned)((wv >> 48) & 0xFFFFull);
              e0 = root[e0]; e1 = root[e1]; e2 = root[e2]; e3 = root[e3];
              root64[idx] = (unsigned long long)e0 | ((unsigned long long)e1 << 16) |
                            ((unsigned long long)e2 << 32) | ((unsigned long long)e3 << 48);
            }
          }
        }
      }
    }
  };

  // prefetch ring: chunk of 4 groups, loads issued one chunk ahead
  unsigned short D0 = onbr[lane], D1 = onbr[64 + lane],
                 D2 = onbr[128 + lane], D3 = onbr[192 + lane];
  int4 I0 = ord4[0], I1 = ord4[1], I2 = ord4[2], I3 = ord4[3];
  for (int g = 0; g < NG; g += 4) {
    unsigned short N0 = 0, N1 = 0, N2 = 0, N3 = 0;
    int4 J0 = make_int4(0, 0, 0, 0), J1 = J0, J2 = J0, J3 = J0;
    if (g + 4 < NG) { N0 = onbr[(g + 4) * 64 + lane]; J0 = ord4[g + 4]; }
    if (g + 5 < NG) { N1 = onbr[(g + 5) * 64 + lane]; J1 = ord4[g + 5]; }
    if (g + 6 < NG) { N2 = onbr[(g + 6) * 64 + lane]; J2 = ord4[g + 6]; }
    if (g + 7 < NG) { N3 = onbr[(g + 7) * 64 + lane]; J3 = ord4[g + 7]; }
    process(D0, I0);
    process(D1, I1);
    process(D2, I2);
    process(D3, I3);
    D0 = N0; D1 = N1; D2 = N2; D3 = N3;
    I0 = J0; I1 = J1; I2 = J2; I3 = J3;
  }
  if (lane == 0) death[order[0]] = scali[0];  // essential pair
}

// ---------------- loss: top-10 persistence, l_change + l_salient (f32 out) ----------------
__global__ __launch_bounds__(256) void loss_kernel(const float* __restrict__ kde,
                                                   const int* __restrict__ death,
                                                   float* __restrict__ out) {
  __shared__ float redv[256];
  __shared__ int redi[256];
  const int t = threadIdx.x;
  int chosen[DESTNUM];
  for (int k = 0; k < DESTNUM; ++k) {
    float bv = -__builtin_inff();
    int bi = 1 << 30;
    for (int p = t; p < NPTS; p += 256) {
      int d = death[p];
      if (d < 0) continue;
      bool used = false;
      for (int c = 0; c < k; ++c) used |= (chosen[c] == p);
      if (used) continue;
      float pers = kde[p] - kde[d];
      if (pers > bv || (pers == bv && p < bi)) { bv = pers; bi = p; }
    }
    redv[t] = bv; redi[t] = bi;
    __syncthreads();
    for (int s = 128; s; s >>= 1) {
      if (t < s) {
        if (redv[t + s] > redv[t] || (redv[t + s] == redv[t] && redi[t + s] < redi[t])) {
          redv[t] = redv[t + s];
          redi[t] = redi[t + s];
        }
      }
      __syncthreads();
    }
    chosen[k] = redi[0];
    __syncthreads();
  }
  float acc = 0.f;
  for (int p = t; p < NPTS; p += 256) {
    int d = death[p];
    if (d < 0) continue;
    bool sal = false;
    for (int c = 0; c < DESTNUM; ++c) sal |= (chosen[c] == p);
    float dv = kde[d];
    float kp = kde[p];
    acc += sal ? ((kp - 1.f) * (kp - 1.f) + dv * dv) : (kp - dv) * (kp - dv);
  }
  redv[t] = acc;
  __syncthreads();
  for (int s = 128; s; s >>= 1) {
    if (t < s) redv[t] += redv[t + s];
    __syncthreads();
  }
  if (t == 0) out[0] = redv[0];
}

extern "C" void kernel_launch(void* const* d_in, const int* in_sizes, int n_in,
                              void* d_out, int out_size, void* d_ws, size_t ws_size,
                              hipStream_t stream) {
  const unsigned short* x = (const unsigned short*)d_in[0];

  float* kde = (float*)d_ws;                      // NPTS f32
  float* scalf = kde + NPTS;                      // [0] = kdemax
  int* scali = (int*)(scalf + 64);                // [0] = argmin idx
  int* flag = scali + 64;                         // [0] = dtype flag (1=bf16, 0=f32)
  int* order = flag + 64;                         // NPTS (16B-aligned for int4 loads)
  int* rankp = order + NPTS;                      // NPTS
  int* rips = rankp + NPTS;                       // NPTS*KRIPS
  unsigned short* onbr = (unsigned short*)(rips + NPTS * KRIPS);  // NPTS*KRIPS u16
  int* death = (int*)(onbr + NPTS * KRIPS);       // NPTS

  hipLaunchKernelGGL(detect_kernel, dim3(1), dim3(64), 0, stream, x, flag);
  hipLaunchKernelGGL(knn_kernel, dim3(NPTS), dim3(256), 0, stream, x, flag, kde, rips);
  hipLaunchKernelGGL(max_kernel, dim3(1), dim3(256), 0, stream, kde, scalf);
  hipLaunchKernelGGL(norm_kernel, dim3(NPTS / 256), dim3(256), 0, stream, kde, scalf, death);
  hipLaunchKernelGGL(argmin_kernel, dim3(1), dim3(256), 0, stream, kde, scali);
  hipLaunchKernelGGL(sort_kernel, dim3(1), dim3(256), 0, stream, kde, order, rankp);
  hipLaunchKernelGGL(onbr_kernel, dim3(NPTS * KRIPS / 256), dim3(256), 0, stream,
                     order, rankp, rips, onbr);
  hipLaunchKernelGGL(scan_kernel, dim3(1), dim3(64), 0, stream, kde, order, onbr, death, scali);
  hipLaunchKernelGGL(loss_kernel, dim3(1), dim3(256), 0, stream, kde, death, (float*)d_out);
}

// Round 14
// 1798.654 us; speedup vs baseline: 4.1526x; 1.1429x over previous
//
#include <hip/hip_runtime.h>
#include <hip/hip_bf16.h>

#define NPTS 8192
#define DIM 32
#define KKDE 32
#define KRIPS 16
#define DESTNUM 10

__device__ __forceinline__ unsigned long long shfl_xor_u64(unsigned long long v, int m) {
  int lo = __shfl_xor((int)(unsigned)(v & 0xFFFFFFFFull), m, 64);
  int hi = __shfl_xor((int)(unsigned)(v >> 32), m, 64);
  return (((unsigned long long)(unsigned)hi) << 32) | (unsigned)lo;
}

// ---------------- dtype detector: is x bf16-packed or f32? ----------------
__global__ __launch_bounds__(64) void detect_kernel(const unsigned short* __restrict__ x,
                                                    int* __restrict__ flag) {
  int lane = threadIdx.x;
  unsigned u = x[2 * lane];
  int e = (u >> 7) & 0xFF;
  bool pass = (e >= 110 && e <= 130);
  unsigned long long b = __ballot(pass);
  if (lane == 0) flag[0] = (__popcll(b) >= 32) ? 1 : 0;
}

// ---------------- transpose: xT[q][p] = x[p][q] as f32 (exact) ----------------
// Coalesced reads; scattered writes (one-off, ~1 MB). Removes the 64-beat
// divergent loads from knn's hot loop.
__global__ __launch_bounds__(256) void tr_kernel(const unsigned short* __restrict__ xh,
                                                 const int* __restrict__ flag,
                                                 float* __restrict__ xT) {
  int e = blockIdx.x * 256 + threadIdx.x;  // < NPTS*DIM
  if (e >= NPTS * DIM) return;
  int p = e >> 5, q = e & 31;
  float v;
  if (flag[0] != 0) v = __uint_as_float(((unsigned)xh[e]) << 16);
  else v = ((const float*)xh)[e];
  xT[q * NPTS + p] = v;
}

// ---------------- kNN v4: coalesced xT compute + per-wave bracket select ----------------
// One block per row i. d2 bitwise-identical to R13 (same fma chains over the same
// values; j==i gives dot==sqi==sqj -> exact 0). Selection machinery = R12/R13
// proven verbatim.
__global__ __launch_bounds__(256) void knn_kernel(const float* __restrict__ xT,
                                                  float* __restrict__ kde,
                                                  int* __restrict__ rips) {
  __shared__ float row[NPTS];                  // 32 KB
  __shared__ int cnt[4];
  __shared__ unsigned long long cand[4 * 64];  // 2 KB
  __shared__ unsigned long long srt[4 * 32];   // 1 KB
  __shared__ unsigned long long fin[64];       // 512 B
  __shared__ float knnv[KKDE];
  __shared__ int knni[KKDE];
  __shared__ float xis[DIM];
  const int i = blockIdx.x;
  const int t = threadIdx.x;
  const int w = t >> 6, lane = t & 63;
  if (t < DIM) xis[t] = xT[t * NPTS + i];
  __syncthreads();
  float xi[DIM];
#pragma unroll
  for (int q = 0; q < DIM; ++q) xi[q] = xis[q];
  float sqi = 0.f;
#pragma unroll
  for (int q = 0; q < DIM; ++q) sqi = fmaf(xi[q], xi[q], sqi);
  // ---- compute phase: coalesced column reads; d2 row into LDS ----
  for (int j = t; j < NPTS; j += 256) {
    float dot = 0.f, sqj = 0.f;
#pragma unroll
    for (int q = 0; q < DIM; ++q) {
      float v = xT[q * NPTS + j];
      dot = fmaf(xi[q], v, dot);
      sqj = fmaf(v, v, sqj);
    }
    // j==i: v==xi[q] bitwise -> dot==sqi==sqj -> fmaf(-2,s,2s) == 0 exactly
    row[j] = fmaxf(fmaf(-2.f, dot, sqi + sqj), 0.f);
  }
  __syncthreads();
  // ---- per-wave bracket: smallest T with count(<=T) >= 32 (count <= 64) ----
  const float4* rowf4 = (const float4*)row;
  unsigned lo = 0u, hi = 0x7F800000u;
  int chi = 2048;
  while (chi > 64 && (hi - lo) > 1u) {
    const unsigned mid = lo + ((hi - lo) >> 1);
    int c = 0;
#pragma unroll
    for (int s = 0; s < 8; ++s) {
      float4 v = rowf4[(w << 9) + (s << 6) + lane];
      c += (__float_as_uint(v.x) <= mid) ? 1 : 0;
      c += (__float_as_uint(v.y) <= mid) ? 1 : 0;
      c += (__float_as_uint(v.z) <= mid) ? 1 : 0;
      c += (__float_as_uint(v.w) <= mid) ? 1 : 0;
    }
#pragma unroll
    for (int m = 1; m <= 32; m <<= 1) c += __shfl_xor(c, m, 64);
    if (c >= 32) { hi = mid; chi = c; } else { lo = mid; }
  }
  // ---- compact candidates ----
  if (lane == 0) cnt[w] = 0;
  cand[(w << 6) | lane] = ~0ull;
#pragma unroll
  for (int s = 0; s < 8; ++s) {
    const int fidx = (w << 9) + (s << 6) + lane;
    float4 v = rowf4[fidx];
    const unsigned b0 = __float_as_uint(v.x), b1 = __float_as_uint(v.y);
    const unsigned b2 = __float_as_uint(v.z), b3 = __float_as_uint(v.w);
    if (b0 <= hi) {
      int pos = atomicAdd(&cnt[w], 1);
      if (pos < 64) cand[(w << 6) + pos] = (((unsigned long long)b0) << 32) | (unsigned)(fidx * 4 + 0);
    }
    if (b1 <= hi) {
      int pos = atomicAdd(&cnt[w], 1);
      if (pos < 64) cand[(w << 6) + pos] = (((unsigned long long)b1) << 32) | (unsigned)(fidx * 4 + 1);
    }
    if (b2 <= hi) {
      int pos = atomicAdd(&cnt[w], 1);
      if (pos < 64) cand[(w << 6) + pos] = (((unsigned long long)b2) << 32) | (unsigned)(fidx * 4 + 2);
    }
    if (b3 <= hi) {
      int pos = atomicAdd(&cnt[w], 1);
      if (pos < 64) cand[(w << 6) + pos] = (((unsigned long long)b3) << 32) | (unsigned)(fidx * 4 + 3);
    }
  }
  // ---- in-wave bitonic sort of 64 keys ----
  unsigned long long v = cand[(w << 6) | lane];
#pragma unroll
  for (int k = 2; k <= 64; k <<= 1) {
#pragma unroll
    for (int j = 32; j > 0; j >>= 1) {
      if (j >= k) continue;
      unsigned long long o = shfl_xor_u64(v, j);
      bool keepMin = (((lane & k) == 0) == ((lane & j) == 0));
      v = keepMin ? (v < o ? v : o) : (v > o ? v : o);
    }
  }
  if (lane < 32) srt[(w << 5) | lane] = v;
  __syncthreads();
  // ---- merge round 1 ----
  if (w < 2) {
    const unsigned long long* A = &srt[(w * 2) << 5];
    const unsigned long long* B = &srt[(w * 2 + 1) << 5];
    unsigned long long m = (lane < 32) ? A[lane] : B[63 - lane];
#pragma unroll
    for (int j = 32; j > 0; j >>= 1) {
      unsigned long long o = shfl_xor_u64(m, j);
      bool keepMin = ((lane & j) == 0);
      m = keepMin ? (m < o ? m : o) : (m > o ? m : o);
    }
    if (lane < 32) fin[(w << 5) | lane] = m;
  }
  __syncthreads();
  // ---- merge round 2 ----
  if (w == 0) {
    unsigned long long m = (lane < 32) ? fin[lane] : fin[32 + (63 - lane)];
#pragma unroll
    for (int j = 32; j > 0; j >>= 1) {
      unsigned long long o = shfl_xor_u64(m, j);
      bool keepMin = ((lane & j) == 0);
      m = keepMin ? (m < o ? m : o) : (m > o ? m : o);
    }
    if (lane < 32) {
      knnv[lane] = __uint_as_float((unsigned)(m >> 32));
      knni[lane] = (int)(m & 0x1FFFull);
    }
  }
  __syncthreads();
  if (t == 0) {
    float s = 0.f;
    for (int k = 0; k < KKDE; ++k) s += expf(knnv[k] * -0.015625f);  // exp(-d2/64), ascending
    kde[i] = s;
  }
  if (t < KRIPS) rips[i * KRIPS + t] = knni[t];
}

// ---------------- max(kde) ----------------
__global__ __launch_bounds__(256) void max_kernel(const float* __restrict__ kde,
                                                  float* __restrict__ scalf) {
  __shared__ float red[256];
  int t = threadIdx.x;
  float m = 0.f;
  for (int p = t; p < NPTS; p += 256) m = fmaxf(m, kde[p]);
  red[t] = m;
  __syncthreads();
  for (int s = 128; s; s >>= 1) {
    if (t < s) red[t] = fmaxf(red[t], red[t + s]);
    __syncthreads();
  }
  if (t == 0) scalf[0] = red[0];
}

// ---------------- normalize + init death ----------------
__global__ __launch_bounds__(256) void norm_kernel(float* __restrict__ kde,
                                                   const float* __restrict__ scalf,
                                                   int* __restrict__ death) {
  int p = blockIdx.x * 256 + threadIdx.x;
  if (p < NPTS) {
    kde[p] = kde[p] / scalf[0];
    death[p] = -1;
  }
}

// ---------------- argmin(kde) ----------------
__global__ __launch_bounds__(256) void argmin_kernel(const float* __restrict__ kde,
                                                     int* __restrict__ scali) {
  __shared__ unsigned long long red[256];
  int t = threadIdx.x;
  unsigned long long best = ~0ull;
  for (int p = t; p < NPTS; p += 256) {
    unsigned long long kk = (((unsigned long long)__float_as_uint(kde[p])) << 32) | (unsigned)p;
    if (kk < best) best = kk;
  }
  red[t] = best;
  __syncthreads();
  for (int s = 128; s; s >>= 1) {
    if (t < s && red[t + s] < red[t]) red[t] = red[t + s];
    __syncthreads();
  }
  if (t == 0) scali[0] = (int)(red[0] & 0xFFFFFFFFull);
}

// ---------------- bitonic sort: order = argsort(-kde) (stable), rank = inverse ----------------
__global__ __launch_bounds__(256) void sort_kernel(const float* __restrict__ kde,
                                                   int* __restrict__ order,
                                                   int* __restrict__ rankp) {
  __shared__ float kv[NPTS];            // 32 KB
  __shared__ unsigned short ki[NPTS];   // 16 KB
  int t = threadIdx.x;
  for (int p = t; p < NPTS; p += 256) { kv[p] = kde[p]; ki[p] = (unsigned short)p; }
  __syncthreads();
  for (int size = 2; size <= NPTS; size <<= 1) {
    for (int stride = size >> 1; stride > 0; stride >>= 1) {
      for (int q = t; q < NPTS / 2; q += 256) {
        int lo = ((q & ~(stride - 1)) << 1) | (q & (stride - 1));
        int hi = lo + stride;
        float va = kv[lo], vb = kv[hi];
        int ia = ki[lo], ib = ki[hi];
        bool aFirst = (va > vb) || (va == vb && ia < ib);
        bool up = ((lo & size) == 0);
        if (up != aFirst) {
          kv[lo] = vb; kv[hi] = va;
          ki[lo] = (unsigned short)ib; ki[hi] = (unsigned short)ia;
        }
      }
      __syncthreads();
    }
  }
  for (int p = t; p < NPTS; p += 256) {
    int idx = ki[p];
    order[p] = idx;
    rankp[idx] = p;
  }
}

// ---------------- ordered neighbor stream (flat: [t*16 + kk]) ----------------
__global__ __launch_bounds__(256) void onbr_kernel(const int* __restrict__ order,
                                                   const int* __restrict__ rankp,
                                                   const int* __restrict__ rips,
                                                   unsigned short* __restrict__ onbr) {
  int e = blockIdx.x * 256 + threadIdx.x;  // e < NPTS*KRIPS
  if (e >= NPTS * KRIPS) return;
  int t = e >> 4, kk = e & 15;
  int i = order[t];
  int nbr = rips[i * KRIPS + kk];
  bool valid = rankp[nbr] < t;  // self has rank == t -> invalid, matching ref
  onbr[e] = (unsigned short)(nbr | (valid ? 0x8000 : 0));
}

// ---------------- persistence scan: eager union-find + prefetch-4 ring (R13 proven) ----------------
__global__ __launch_bounds__(64) void scan_kernel(const float* __restrict__ kde,
                                                  const int* __restrict__ order,
                                                  const unsigned short* __restrict__ onbr,
                                                  int* __restrict__ death,
                                                  const int* __restrict__ scali) {
  __shared__ float kdeS[NPTS];          // 32 KB
  __shared__ unsigned short root[NPTS]; // 16 KB
  const int lane = threadIdx.x;
  for (int p = lane; p < NPTS; p += 64) { kdeS[p] = kde[p]; root[p] = (unsigned short)p; }
  __syncthreads();
  const int sg = lane >> 4;
  const int4* ord4 = (const int4*)order;
  unsigned long long* root64 = (unsigned long long*)root;
  const int NG = NPTS / 4;

  auto process = [&](unsigned short cD, int4 cI) {
    const int di = cD;
    const int nbr = di & 0x1FFF;
    const bool valid = (di & 0x8000) != 0;
    const int iMine = (sg == 0) ? cI.x : (sg == 1) ? cI.y : (sg == 2) ? cI.z : cI.w;
    const int rd = root[nbr];           // single-hop find (invariant)
    const unsigned long long vbAll = __ballot(valid);
    const unsigned long long vb0 = vbAll & 0xFFFFull;
    const unsigned long long vb1 = (vbAll >> 16) & 0xFFFFull;
    const unsigned long long vb2 = (vbAll >> 32) & 0xFFFFull;
    const unsigned long long vb3 = (vbAll >> 48) & 0xFFFFull;
    const int gc0 = vb0 ? __builtin_amdgcn_readlane(rd, __ffsll(vb0) - 1) : cI.x;
    const int gc1 = vb1 ? __builtin_amdgcn_readlane(rd, 16 + __ffsll(vb1) - 1) : cI.y;
    const int gc2 = vb2 ? __builtin_amdgcn_readlane(rd, 32 + __ffsll(vb2) - 1) : cI.z;
    const int gc3 = vb3 ? __builtin_amdgcn_readlane(rd, 48 + __ffsll(vb3) - 1) : cI.w;
    const int gcMine = (sg == 0) ? gc0 : (sg == 1) ? gc1 : (sg == 2) ? gc2 : gc3;
    const bool uniOk = !valid || (rd == gcMine);
    const bool collide =
        valid && (rd == cI.x || rd == cI.y || rd == cI.z || rd == cI.w);
    if (__all(uniOk && !collide)) {
      if ((lane & 15) == 0) root[iMine] = (unsigned short)gcMine;
    } else {
#pragma unroll
      for (int s = 0; s < 4; ++s) {
        const unsigned long long smask = 0xFFFFull << (16 * s);
        const int rc = (s == 0) ? rd : (int)root[nbr];
        unsigned long long vb = vbAll & smask;
        if (vb != 0) {
          int cl = __ffsll(vb) - 1;
          int gc = __builtin_amdgcn_readlane(rc, cl);
          unsigned long long uni = __ballot(!valid || rc == gc) & smask;
          if (uni == smask) {
            if (lane == 16 * s) root[iMine] = (unsigned short)gc;
          } else {
            float kr = valid ? kdeS[rc] : -1.0f;
            float mx = kr;
#pragma unroll
            for (int mk = 1; mk <= 8; mk <<= 1) mx = fmaxf(mx, __shfl_xor(mx, mk, 64));
            unsigned long long b = __ballot(valid && kr == mx) & smask;
            int kwin = __ffsll(b) - 1;
            int g = __builtin_amdgcn_readlane(rc, kwin);
            bool dying = (sg == s) && valid && (rc != g);
            if (dying) {
              root[rc] = (unsigned short)g;
              death[rc] = iMine;
            }
            if (lane == 16 * s) root[iMine] = (unsigned short)g;
#pragma unroll 1
            for (int it = 0; it < NPTS / 256; ++it) {
              int idx = it * 64 + lane;
              unsigned long long wv = root64[idx];
              unsigned e0 = (unsigned)(wv & 0xFFFFull);
              unsigned e1 = (unsigned)((wv >> 16) & 0xFFFFull);
              unsigned e2 = (unsigned)((wv >> 32) & 0xFFFFull);
              unsigned e3 = (unsigned)((wv >> 48) & 0xFFFFull);
              e0 = root[e0]; e1 = root[e1]; e2 = root[e2]; e3 = root[e3];
              root64[idx] = (unsigned long long)e0 | ((unsigned long long)e1 << 16) |
                            ((unsigned long long)e2 << 32) | ((unsigned long long)e3 << 48);
            }
          }
        }
      }
    }
  };

  unsigned short D0 = onbr[lane], D1 = onbr[64 + lane],
                 D2 = onbr[128 + lane], D3 = onbr[192 + lane];
  int4 I0 = ord4[0], I1 = ord4[1], I2 = ord4[2], I3 = ord4[3];
  for (int g = 0; g < NG; g += 4) {
    unsigned short N0 = 0, N1 = 0, N2 = 0, N3 = 0;
    int4 J0 = make_int4(0, 0, 0, 0), J1 = J0, J2 = J0, J3 = J0;
    if (g + 4 < NG) { N0 = onbr[(g + 4) * 64 + lane]; J0 = ord4[g + 4]; }
    if (g + 5 < NG) { N1 = onbr[(g + 5) * 64 + lane]; J1 = ord4[g + 5]; }
    if (g + 6 < NG) { N2 = onbr[(g + 6) * 64 + lane]; J2 = ord4[g + 6]; }
    if (g + 7 < NG) { N3 = onbr[(g + 7) * 64 + lane]; J3 = ord4[g + 7]; }
    process(D0, I0);
    process(D1, I1);
    process(D2, I2);
    process(D3, I3);
    D0 = N0; D1 = N1; D2 = N2; D3 = N3;
    I0 = J0; I1 = J1; I2 = J2; I3 = J3;
  }
  if (lane == 0) death[order[0]] = scali[0];  // essential pair
}

// ---------------- loss: top-10 persistence, l_change + l_salient (f32 out) ----------------
__global__ __launch_bounds__(256) void loss_kernel(const float* __restrict__ kde,
                                                   const int* __restrict__ death,
                                                   float* __restrict__ out) {
  __shared__ float redv[256];
  __shared__ int redi[256];
  const int t = threadIdx.x;
  int chosen[DESTNUM];
  for (int k = 0; k < DESTNUM; ++k) {
    float bv = -__builtin_inff();
    int bi = 1 << 30;
    for (int p = t; p < NPTS; p += 256) {
      int d = death[p];
      if (d < 0) continue;
      bool used = false;
      for (int c = 0; c < k; ++c) used |= (chosen[c] == p);
      if (used) continue;
      float pers = kde[p] - kde[d];
      if (pers > bv || (pers == bv && p < bi)) { bv = pers; bi = p; }
    }
    redv[t] = bv; redi[t] = bi;
    __syncthreads();
    for (int s = 128; s; s >>= 1) {
      if (t < s) {
        if (redv[t + s] > redv[t] || (redv[t + s] == redv[t] && redi[t + s] < redi[t])) {
          redv[t] = redv[t + s];
          redi[t] = redi[t + s];
        }
      }
      __syncthreads();
    }
    chosen[k] = redi[0];
    __syncthreads();
  }
  float acc = 0.f;
  for (int p = t; p < NPTS; p += 256) {
    int d = death[p];
    if (d < 0) continue;
    bool sal = false;
    for (int c = 0; c < DESTNUM; ++c) sal |= (chosen[c] == p);
    float dv = kde[d];
    float kp = kde[p];
    acc += sal ? ((kp - 1.f) * (kp - 1.f) + dv * dv) : (kp - dv) * (kp - dv);
  }
  redv[t] = acc;
  __syncthreads();
  for (int s = 128; s; s >>= 1) {
    if (t < s) redv[t] += redv[t + s];
    __syncthreads();
  }
  if (t == 0) out[0] = redv[0];
}

extern "C" void kernel_launch(void* const* d_in, const int* in_sizes, int n_in,
                              void* d_out, int out_size, void* d_ws, size_t ws_size,
                              hipStream_t stream) {
  const unsigned short* x = (const unsigned short*)d_in[0];

  float* xT = (float*)d_ws;                       // NPTS*DIM f32 transposed (1 MB)
  float* kde = xT + NPTS * DIM;                   // NPTS f32
  float* scalf = kde + NPTS;                      // [0] = kdemax
  int* scali = (int*)(scalf + 64);                // [0] = argmin idx
  int* flag = scali + 64;                         // [0] = dtype flag (1=bf16, 0=f32)
  int* order = flag + 64;                         // NPTS (16B-aligned for int4 loads)
  int* rankp = order + NPTS;                      // NPTS
  int* rips = rankp + NPTS;                       // NPTS*KRIPS
  unsigned short* onbr = (unsigned short*)(rips + NPTS * KRIPS);  // NPTS*KRIPS u16
  int* death = (int*)(onbr + NPTS * KRIPS);       // NPTS

  hipLaunchKernelGGL(detect_kernel, dim3(1), dim3(64), 0, stream, x, flag);
  hipLaunchKernelGGL(tr_kernel, dim3(NPTS * DIM / 256), dim3(256), 0, stream, x, flag, xT);
  hipLaunchKernelGGL(knn_kernel, dim3(NPTS), dim3(256), 0, stream, xT, kde, rips);
  hipLaunchKernelGGL(max_kernel, dim3(1), dim3(256), 0, stream, kde, scalf);
  hipLaunchKernelGGL(norm_kernel, dim3(NPTS / 256), dim3(256), 0, stream, kde, scalf, death);
  hipLaunchKernelGGL(argmin_kernel, dim3(1), dim3(256), 0, stream, kde, scali);
  hipLaunchKernelGGL(sort_kernel, dim3(1), dim3(256), 0, stream, kde, order, rankp);
  hipLaunchKernelGGL(onbr_kernel, dim3(NPTS * KRIPS / 256), dim3(256), 0, stream,
                     order, rankp, rips, onbr);
  hipLaunchKernelGGL(scan_kernel, dim3(1), dim3(64), 0, stream, kde, order, onbr, death, scali);
  hipLaunchKernelGGL(loss_kernel, dim3(1), dim3(256), 0, stream, kde, death, (float*)d_out);
}